// Round 4
// baseline (342.313 us; speedup 1.0000x reference)
//
#include <hip/hip_runtime.h>

#define NN 50000
#define E0 200000
#define E2 400000
#define NGROUPS ((NN + 7) / 8)      // 6250 (×8 = 50000 exactly)
#define NCHUNK  ((NN + 255) / 256)  // 196
#define NTILES  ((NN + 63) / 64)    // 782
#define EB      ((E2 + 255) / 256)  // 1563

typedef __attribute__((ext_vector_type(8))) short short8;
typedef __attribute__((ext_vector_type(4))) float f32x4;

__device__ __forceinline__ float eluf(float x) { return x > 0.0f ? x : expm1f(x); }
__device__ __forceinline__ float fsig(float x) { return 1.0f / (1.0f + __expf(-x)); }
__device__ __forceinline__ float ftanh(float x) {
    float e = __expf(-2.0f * x);
    return (1.0f - e) / (1.0f + e);
}
__device__ __forceinline__ unsigned rne_bf16(float x) {
    unsigned u = __float_as_uint(x);
    return (u + 0x7fffu + ((u >> 16) & 1u)) >> 16;
}

// ---------------- single-wave spectral norm: lane r holds u[r]; matvecs via shfl broadcast;
// LDS stride-33 is bank-conflict-free for BOTH row and column access; no __syncthreads in loop.
__device__ __forceinline__ void spectral_block(int l, const float* __restrict__ Wl_in,
                                               const float* __restrict__ Wr_in,
                                               float* __restrict__ Wl_out, float* __restrict__ Wr_out) {
    __shared__ float W[32 * 33];
    __shared__ float sscal;
    int t = threadIdx.x;
    for (int i = t; i < 1024; i += 256) W[(i >> 5) * 33 + (i & 31)] = Wr_in[l * 1024 + i];
    __syncthreads();
    if (t < 32) {
        float u = 0.17677669529663688f;     // 1/sqrt(32), lane r holds u[r]
        for (int it = 0; it < 20; ++it) {
            float v = 0.f;                   // v[c] = sum_r W[r][c] * u[r]  (lane c)
#pragma unroll 8
            for (int r = 0; r < 32; ++r) v = fmaf(W[r * 33 + t], __shfl(u, r, 32), v);
            float s = v * v;
#pragma unroll
            for (int off = 16; off; off >>= 1) s += __shfl_xor(s, off, 32);
            v *= 1.0f / (sqrtf(s) + 1e-12f);
            float u2 = 0.f;                  // u2[r] = sum_c W[r][c] * v[c]  (lane r)
#pragma unroll 8
            for (int c = 0; c < 32; ++c) u2 = fmaf(W[t * 33 + c], __shfl(v, c, 32), u2);
            s = u2 * u2;
#pragma unroll
            for (int off = 16; off; off >>= 1) s += __shfl_xor(s, off, 32);
            u = u2 * (1.0f / (sqrtf(s) + 1e-12f));
        }
        // sigma: v = W^T u (final); s = ||v||^2 ; 1/sigma = (sqrt(s)+1e-12)/s  (matches ref)
        float v = 0.f;
#pragma unroll 8
        for (int r = 0; r < 32; ++r) v = fmaf(W[r * 33 + t], __shfl(u, r, 32), v);
        float s = v * v;
#pragma unroll
        for (int off = 16; off; off >>= 1) s += __shfl_xor(s, off, 32);
        if (t == 0) sscal = (sqrtf(s) + 1e-12f) / s;
    } else if (t == 64) {                    // Wl 3x3 power iteration on wave 1, concurrent
        float M[9];
        for (int i = 0; i < 9; ++i) M[i] = Wl_in[l * 9 + i];
        float u[3] = {0.5773502691896258f, 0.5773502691896258f, 0.5773502691896258f};
        float v[3], u2[3];
        for (int it = 0; it < 20; ++it) {
            float s = 0;
            for (int c = 0; c < 3; ++c) { v[c] = M[c] * u[0] + M[3 + c] * u[1] + M[6 + c] * u[2]; s += v[c] * v[c]; }
            float inv = 1.0f / (sqrtf(s) + 1e-12f);
            for (int c = 0; c < 3; ++c) v[c] *= inv;
            s = 0;
            for (int r = 0; r < 3; ++r) { u2[r] = M[r * 3] * v[0] + M[r * 3 + 1] * v[1] + M[r * 3 + 2] * v[2]; s += u2[r] * u2[r]; }
            inv = 1.0f / (sqrtf(s) + 1e-12f);
            for (int r = 0; r < 3; ++r) u[r] = u2[r] * inv;
        }
        float s = 0;
        for (int c = 0; c < 3; ++c) { v[c] = M[c] * u[0] + M[3 + c] * u[1] + M[6 + c] * u[2]; s += v[c] * v[c]; }
        float inv = (sqrtf(s) + 1e-12f) / s;
        for (int i = 0; i < 9; ++i) Wl_out[l * 9 + i] = M[i] * inv;
    }
    __syncthreads();
    float invs = sscal;
    for (int i = t; i < 1024; i += 256) Wr_out[l * 1024 + i] = W[(i >> 5) * 33 + (i & 31)] * invs;
}

// ---------------- setup: blocks 0,1 = spectral norm per layer; rest zero counters
__global__ __launch_bounds__(256) void k_setup(const float* __restrict__ Wl_in, const float* __restrict__ Wr_in,
                                               float* __restrict__ Wl_out, float* __restrict__ Wr_out,
                                               int* __restrict__ cnt, int* __restrict__ fill,
                                               float* __restrict__ deg0, int* __restrict__ gtotal) {
    if (blockIdx.x < 2) {
        spectral_block((int)blockIdx.x, Wl_in, Wr_in, Wl_out, Wr_out);
        return;
    }
    int i = (blockIdx.x - 2) * 256 + threadIdx.x;
    if (i == 0) *gtotal = 0;
    if (i < NN) { cnt[i] = 0; fill[i] = 0; deg0[i] = 0.0f; }
}

// ---------------- MFMA GEMM: multi-tile grid-stride + N column-split
template<int K, int N, int NH, bool ELU, bool HIST>
__global__ __launch_bounds__(256) void k_gemm(const float* __restrict__ X,
                                              const float* __restrict__ W,
                                              const float* __restrict__ bias,
                                              float* __restrict__ out,
                                              const int* __restrict__ row, int* __restrict__ cnt) {
    constexpr int KP = K + 8;
    constexpr int NT = NH / 16;
    constexpr int KS = K / 32;
    constexpr int NHALVES = N / NH;
    __shared__ __align__(16) unsigned short whi[NH * KP];
    __shared__ __align__(16) unsigned short wlo[NH * KP];
    int tid = threadIdx.x;
    if (HIST) {   // independent atomics first; latency hides behind GEMM
        for (int e = blockIdx.x * 256 + tid; e < E2; e += gridDim.x * 256)
            atomicAdd(&cnt[row[e]], 1);
    }
    const int ch = blockIdx.x % NHALVES;
    const int tstream = blockIdx.x / NHALVES;
    const int nstreams = gridDim.x / NHALVES;
    for (int i = tid; i < NH * K; i += 256) {
        float v = W[ch * NH * K + i];
        int r = i / K, c = i % K;
        unsigned h = rne_bf16(v);
        whi[r * KP + c] = (unsigned short)h;
        wlo[r * KP + c] = (unsigned short)rne_bf16(v - __uint_as_float(h << 16));
    }
    __syncthreads();
    int wave = tid >> 6, lane = tid & 63;
    int quad = lane >> 4, r16 = lane & 15;
    for (int t = tstream; t < NTILES; t += nstreams) {
        long m = (long)t * 64 + wave * 16 + r16;
        long mc = m < NN ? m : (NN - 1);
        const float* xrow = X + mc * K + quad * 8;
        short8 ah[KS], al[KS];
#pragma unroll
        for (int ks = 0; ks < KS; ++ks) {
            const float4* xp = (const float4*)(xrow + ks * 32);
            float4 p0 = xp[0], p1 = xp[1];
            float xv[8] = {p0.x, p0.y, p0.z, p0.w, p1.x, p1.y, p1.z, p1.w};
#pragma unroll
            for (int j = 0; j < 8; ++j) {
                unsigned h = rne_bf16(xv[j]);
                ah[ks][j] = (short)h;
                al[ks][j] = (short)rne_bf16(xv[j] - __uint_as_float(h << 16));
            }
        }
        long mbase = (long)t * 64 + wave * 16 + quad * 4;
#pragma unroll
        for (int tt = 0; tt < NT; ++tt) {
            f32x4 acc = (f32x4){0.f, 0.f, 0.f, 0.f};
#pragma unroll
            for (int ks = 0; ks < KS; ++ks) {
                int ro = (tt * 16 + r16) * KP + ks * 32 + quad * 8;
                short8 bh = *(const short8*)&whi[ro];
                short8 bl = *(const short8*)&wlo[ro];
                acc = __builtin_amdgcn_mfma_f32_16x16x32_bf16(ah[ks], bh, acc, 0, 0, 0);
                acc = __builtin_amdgcn_mfma_f32_16x16x32_bf16(al[ks], bh, acc, 0, 0, 0);
                acc = __builtin_amdgcn_mfma_f32_16x16x32_bf16(ah[ks], bl, acc, 0, 0, 0);
            }
            // C/D layout: col = lane&15, row = quad*4 + reg [m89-verified]
            int coln = ch * NH + tt * 16 + r16;
            float b = bias[coln];
#pragma unroll
            for (int rr = 0; rr < 4; ++rr) {
                long mm = mbase + rr;
                if (mm < NN) {
                    float v = acc[rr] + b;
                    if (ELU) v = eluf(v);
                    out[mm * N + coln] = v;
                }
            }
        }
    }
}

// ---------------- single-pass scan: local prefix + atomic grid offset -> absolute start
__global__ __launch_bounds__(256) void k_scan(const int* __restrict__ cnt, int* __restrict__ start,
                                              int* __restrict__ gtotal) {
    __shared__ int s[256];
    __shared__ int soff;
    int b = blockIdx.x, t = threadIdx.x;
    int i = b * 256 + t;
    int v = (i < NN) ? cnt[i] : 0;
    s[t] = v;
    __syncthreads();
    for (int off = 1; off < 256; off <<= 1) {
        int add = (t >= off) ? s[t - off] : 0;
        __syncthreads();
        s[t] += add;
        __syncthreads();
    }
    if (t == 255) soff = atomicAdd(gtotal, s[255]);   // chunk order nondeterministic; slots stay disjoint
    __syncthreads();
    if (i < NN) start[i] = s[t] - v + soff;
}

// ---------------- fused: blocks [0,NGROUPS) = y8 layer 0 ; [NGROUPS, +EB) = CSR fill
__global__ __launch_bounds__(256) void k_filly8(const float* __restrict__ xc,
                                                const float* __restrict__ Wl, const float* __restrict__ Wr,
                                                const float* __restrict__ Wsh, const float* __restrict__ Wwt,
                                                unsigned* __restrict__ yA, unsigned short* __restrict__ yB,
                                                float4* __restrict__ proj,
                                                const int* __restrict__ row, const int* __restrict__ start,
                                                int* __restrict__ fill, int* __restrict__ eslot) {
    int tid = threadIdx.x;
    if (blockIdx.x >= NGROUPS) {   // CSR fill branch
        int e = (blockIdx.x - NGROUPS) * 256 + tid;
        if (e < E2) {
            int u = row[e];
            eslot[e] = start[u] + atomicAdd(&fill[u], 1);
        }
        return;
    }
    __shared__ float wrs[32 * 33];
    __shared__ float wls[9];
    __shared__ float xcs[8][96];
    __shared__ float ws1[192], wt[192];
    int n0 = blockIdx.x * 8;
    for (int i = tid; i < 1024; i += 256) wrs[(i >> 5) * 33 + (i & 31)] = Wr[i];
    if (tid < 9) wls[tid] = Wl[tid];
    if (tid < 192) {
        ws1[tid] = Wsh[192 + tid];   // layer 0, row 1 of W_sheaf (only row surviving Cayley, D=2)
        wt[tid]  = Wwt[tid];
    }
    for (int i = tid; i < 192; i += 256) {
        int nd = i / 24, of = (i % 24) * 4;
        *(float4*)&xcs[nd][of] = *(const float4*)&xc[(n0 + nd) * 96 + of];
    }
    __syncthreads();
    int node = tid >> 5, c = tid & 31;
    int n = n0 + node;
    float a1 = 0, a2 = 0, a3 = 0, a4 = 0;
#pragma unroll
    for (int j = 0; j < 3; ++j) {
        int k = j * 32 + c;
        float xv = xcs[node][k];
        a1 = fmaf(xv, ws1[k], a1);
        a2 = fmaf(xv, ws1[96 + k], a2);
        a3 = fmaf(xv, wt[k], a3);
        a4 = fmaf(xv, wt[96 + k], a4);
    }
#pragma unroll
    for (int off = 16; off; off >>= 1) {
        a1 += __shfl_xor(a1, off);
        a2 += __shfl_xor(a2, off);
        a3 += __shfl_xor(a3, off);
        a4 += __shfl_xor(a4, off);
    }
    if (c == 0) proj[n] = make_float4(a1, a2, a3, a4);   // {aR, aC, wR, wC}
    {
        float t0 = 0, t1 = 0, t2 = 0;
        const float* wr = &wrs[c * 33];
        const float* xr = xcs[node];
#pragma unroll
        for (int h = 0; h < 32; ++h) {
            float w = wr[h];
            t0 = fmaf(xr[h], w, t0);
            t1 = fmaf(xr[32 + h], w, t1);
            t2 = fmaf(xr[64 + h], w, t2);
        }
        float o0 = wls[0] * t0 + wls[1] * t1 + wls[2] * t2;
        float o1 = wls[3] * t0 + wls[4] * t1 + wls[5] * t2;
        float o2 = wls[6] * t0 + wls[7] * t1 + wls[8] * t2;
        yA[n * 32 + c] = rne_bf16(o0) | (rne_bf16(o1) << 16);
        yB[n * 32 + c] = (unsigned short)rne_bf16(o2);
    }
}

// ---------------- per-edge coefficients, 8B packed meta + degree
__global__ __launch_bounds__(256) void k_coef(const int* __restrict__ row, const int* __restrict__ col,
                                              const int* __restrict__ eslot,
                                              const float4* __restrict__ proj,
                                              uint2* __restrict__ meta, float* __restrict__ deg) {
    int e = blockIdx.x * 256 + threadIdx.x;
    if (e >= E0) return;
    int u = row[e], v = col[e];
    float4 pu = proj[u], pv = proj[v];
    float a_e = ftanh(pu.x + pv.y);
    float a_r = ftanh(pv.x + pu.y);
    float wd_e = fsig(pu.z + pv.w);
    float wd_r = fsig(pv.z + pu.w);
    float w = wd_e * wd_r;
    float w2 = w * w;
    float ie = 1.0f / (1.0f + a_e * a_e), ir = 1.0f / (1.0f + a_r * a_r);
    float ce = (1.0f - a_e * a_e) * ie, se = 2.0f * a_e * ie;
    float cr = (1.0f - a_r * a_r) * ir, sr = 2.0f * a_r * ir;
    float C = ce * cr + se * sr;   // T_e = Q_e^T Q_rev ; T_rev = T_e^T -> (C,-S)
    float S = ce * sr - se * cr;
    unsigned cb = rne_bf16(C), sb = rne_bf16(S), wb = rne_bf16(w2);
    meta[eslot[e]]      = make_uint2(cb | (sb << 16), (unsigned)v | (wb << 16));
    meta[eslot[e + E0]] = make_uint2(cb | ((sb ^ 0x8000u) << 16), (unsigned)u | (wb << 16));
    atomicAdd(&deg[u], w2);
    atomicAdd(&deg[v], w2);
}

// ---------------- gather body (2 nodes/wave, 32-lane halves), 4x-unrolled j-loop
__device__ __forceinline__ void gather_accum(int s0, int ec, int c,
                                             const uint2* __restrict__ meta,
                                             const float* __restrict__ deg, float du,
                                             const unsigned* __restrict__ yA,
                                             const unsigned short* __restrict__ yB,
                                             float& acc0, float& acc1, float& acc2) {
    for (int bs = 0; bs < ec; bs += 32) {
        int nb2 = min(32, ec - bs);
        float CC = 0, SS = 0, cnl = 0;
        int vj = 0;
        if (c < nb2) {
            uint2 mt = meta[s0 + bs + c];
            vj = (int)(mt.y & 0xffffu);
            float w2 = __uint_as_float(mt.y & 0xffff0000u);
            float Cv = __uint_as_float(mt.x << 16);
            float Sv = __uint_as_float(mt.x & 0xffff0000u);
            float dv = deg[vj];
            float dvi = dv > 0.0f ? rsqrtf(fmaxf(dv, 1e-30f)) : 0.0f;
            cnl = w2 * du * dvi;
            CC = cnl * Cv;
            SS = cnl * Sv;
        }
        int j4 = nb2 & ~3;
        int j = 0;
        for (; j < j4; j += 4) {
#pragma unroll
            for (int jj = 0; jj < 4; ++jj) {
                float Cj = __shfl(CC, j + jj, 32);
                float Sj = __shfl(SS, j + jj, 32);
                float cj = __shfl(cnl, j + jj, 32);
                int v = __shfl(vj, j + jj, 32);
                unsigned ua = yA[v * 32 + c];
                unsigned ub = (unsigned)yB[v * 32 + c];
                float y0 = __uint_as_float(ua << 16);
                float y1 = __uint_as_float(ua & 0xffff0000u);
                float y2 = __uint_as_float(ub << 16);
                acc0 = fmaf(Cj, y0, acc0);
                acc0 = fmaf(-Sj, y1, acc0);
                acc1 = fmaf(Sj, y0, acc1);
                acc1 = fmaf(Cj, y1, acc1);
                acc2 = fmaf(cj, y2, acc2);
            }
        }
        for (; j < nb2; ++j) {
            float Cj = __shfl(CC, j, 32);
            float Sj = __shfl(SS, j, 32);
            float cj = __shfl(cnl, j, 32);
            int v = __shfl(vj, j, 32);
            unsigned ua = yA[v * 32 + c];
            unsigned ub = (unsigned)yB[v * 32 + c];
            float y0 = __uint_as_float(ua << 16);
            float y1 = __uint_as_float(ua & 0xffff0000u);
            float y2 = __uint_as_float(ub << 16);
            acc0 = fmaf(Cj, y0, acc0);
            acc0 = fmaf(-Sj, y1, acc0);
            acc1 = fmaf(Sj, y0, acc1);
            acc1 = fmaf(Cj, y1, acc1);
            acc2 = fmaf(cj, y2, acc2);
        }
    }
}

// ---------------- gather layer 0 + residual + FUSED y8 layer 1 (8 nodes/block, 2/wave)
__global__ __launch_bounds__(256) void k_gatherY(const int* __restrict__ start,
                                                 const int* __restrict__ cnt,
                                                 const uint2* __restrict__ meta,
                                                 const float* __restrict__ deg0,
                                                 const unsigned* __restrict__ yA0,
                                                 const unsigned short* __restrict__ yB0,
                                                 const float* __restrict__ eps,
                                                 float* __restrict__ xc,
                                                 const float* __restrict__ Wl, const float* __restrict__ Wr,
                                                 const float* __restrict__ Wsh, const float* __restrict__ Wwt,
                                                 unsigned* __restrict__ yA1, unsigned short* __restrict__ yB1,
                                                 float4* __restrict__ proj, float* __restrict__ deg1) {
    __shared__ float wrs[32 * 33];
    __shared__ float wls[9];
    __shared__ float xcs[8][96];
    __shared__ float ws1[192], wt[192];
    int tid = threadIdx.x;
    int node = tid >> 5, c = tid & 31;
    int n = blockIdx.x * 8 + node;                 // NGROUPS*8 == NN: always in range
    // issue scalar per-node loads before staging so they overlap it
    int s0 = start[n], ec = cnt[n];
    float dn = deg0[n];
    for (int i = tid; i < 1024; i += 256) wrs[(i >> 5) * 33 + (i & 31)] = Wr[i];
    if (tid < 9) wls[tid] = Wl[tid];
    if (tid < 192) {
        ws1[tid] = Wsh[(1 * 3 + 1) * 192 + tid];   // layer 1 sheaf row
        wt[tid]  = Wwt[1 * 192 + tid];
    }
    __syncthreads();                               // weight staging visible to all waves
    float du = dn > 0.0f ? rsqrtf(fmaxf(dn, 1e-30f)) : 0.0f;
    float acc0 = 0, acc1 = 0, acc2 = 0;
    gather_accum(s0, ec, c, meta, deg0, du, yA0, yB0, acc0, acc1, acc2);
    float diag = dn > 0.0f ? 1.0f : 0.0f;
    unsigned ua = yA0[n * 32 + c];
    unsigned ub = (unsigned)yB0[n * 32 + c];
    float oy0 = __uint_as_float(ua << 16);
    float oy1 = __uint_as_float(ua & 0xffff0000u);
    float oy2 = __uint_as_float(ub << 16);
    float c0 = 1.0f + tanhf(eps[0]);
    float c1 = 1.0f + tanhf(eps[1]);
    float c2 = 1.0f + tanhf(eps[2]);
    int base = n * 96 + c;
    float nx0 = c0 * xc[base]      - eluf(diag * oy0 - acc0);
    float nx1 = c1 * xc[base + 32] - eluf(diag * oy1 - acc1);
    float nx2 = c2 * xc[base + 64] - eluf(diag * oy2 - acc2);
    xc[base] = nx0; xc[base + 32] = nx1; xc[base + 64] = nx2;
    if (c == 0) deg1[n] = 0.0f;                    // zero next layer's degree
    xcs[node][c] = nx0; xcs[node][32 + c] = nx1; xcs[node][64 + c] = nx2;
    // NO __syncthreads: layer-1 epilogue reads only xcs[node], written by this same
    // half-warp (intra-wave LDS ordering); waves stay decoupled from slow gathers.
    // ---- layer-1 projections (own channels in registers) ----
    float a1 = nx0 * ws1[c] + nx1 * ws1[32 + c] + nx2 * ws1[64 + c];
    float a2 = nx0 * ws1[96 + c] + nx1 * ws1[128 + c] + nx2 * ws1[160 + c];
    float a3 = nx0 * wt[c] + nx1 * wt[32 + c] + nx2 * wt[64 + c];
    float a4 = nx0 * wt[96 + c] + nx1 * wt[128 + c] + nx2 * wt[160 + c];
#pragma unroll
    for (int off = 16; off; off >>= 1) {
        a1 += __shfl_xor(a1, off);
        a2 += __shfl_xor(a2, off);
        a3 += __shfl_xor(a3, off);
        a4 += __shfl_xor(a4, off);
    }
    if (c == 0) proj[n] = make_float4(a1, a2, a3, a4);
    // ---- layer-1 y ----
    {
        float t0 = 0, t1 = 0, t2 = 0;
        const float* wr = &wrs[c * 33];
        const float* xr = xcs[node];
#pragma unroll
        for (int h = 0; h < 32; ++h) {
            float w = wr[h];
            t0 = fmaf(xr[h], w, t0);
            t1 = fmaf(xr[32 + h], w, t1);
            t2 = fmaf(xr[64 + h], w, t2);
        }
        float o0 = wls[0] * t0 + wls[1] * t1 + wls[2] * t2;
        float o1 = wls[3] * t0 + wls[4] * t1 + wls[5] * t2;
        float o2 = wls[6] * t0 + wls[7] * t1 + wls[8] * t2;
        yA1[n * 32 + c] = rne_bf16(o0) | (rne_bf16(o1) << 16);
        yB1[n * 32 + c] = (unsigned short)rne_bf16(o2);
    }
}

// ---------------- gather layer 1 + residual + FUSED final GEMM (out = xc_new @ W2^T + b2)
__global__ __launch_bounds__(256) void k_gatherF(const int* __restrict__ start,
                                                 const int* __restrict__ cnt,
                                                 const uint2* __restrict__ meta,
                                                 const float* __restrict__ deg,
                                                 const unsigned* __restrict__ yA,
                                                 const unsigned short* __restrict__ yB,
                                                 const float* __restrict__ eps,
                                                 const float* __restrict__ xc,
                                                 const float* __restrict__ W2, const float* __restrict__ b2,
                                                 float* __restrict__ out) {
    __shared__ float w2t[96 * 32];                 // w2t[f*32+o] = W2[o*96+f]
    __shared__ float b2s[32];
    __shared__ float xcs[8][96];
    int tid = threadIdx.x;
    int node = tid >> 5, c = tid & 31;
    int n = blockIdx.x * 8 + node;
    int s0 = start[n], ec = cnt[n];
    float dn = deg[n];
    for (int i = tid; i < 3072; i += 256) {        // linear LDS write; strided global read (12KB, L2)
        int o = i & 31, f = i >> 5;
        w2t[i] = W2[o * 96 + f];
    }
    if (tid < 32) b2s[tid] = b2[tid];
    __syncthreads();
    float du = dn > 0.0f ? rsqrtf(fmaxf(dn, 1e-30f)) : 0.0f;
    float acc0 = 0, acc1 = 0, acc2 = 0;
    gather_accum(s0, ec, c, meta, deg, du, yA, yB, acc0, acc1, acc2);
    float diag = dn > 0.0f ? 1.0f : 0.0f;
    unsigned ua = yA[n * 32 + c];
    unsigned ub = (unsigned)yB[n * 32 + c];
    float oy0 = __uint_as_float(ua << 16);
    float oy1 = __uint_as_float(ua & 0xffff0000u);
    float oy2 = __uint_as_float(ub << 16);
    float c0 = 1.0f + tanhf(eps[3]);
    float c1 = 1.0f + tanhf(eps[4]);
    float c2 = 1.0f + tanhf(eps[5]);
    int base = n * 96 + c;
    float nx0 = c0 * xc[base]      - eluf(diag * oy0 - acc0);
    float nx1 = c1 * xc[base + 32] - eluf(diag * oy1 - acc1);
    float nx2 = c2 * xc[base + 64] - eluf(diag * oy2 - acc2);
    xcs[node][c] = nx0; xcs[node][32 + c] = nx1; xcs[node][64 + c] = nx2;
    // no barrier: xcs[node] written+read by this same half-warp
    // ---- final GEMM row: out[n,o] = sum_f xcs[f] * W2[o,f] + b2[o], lane o=c ----
    float acc = 0.f;
    const float* xr = xcs[node];
#pragma unroll 4
    for (int f = 0; f < 96; ++f) acc = fmaf(xr[f], w2t[f * 32 + c], acc);
    out[n * 32 + c] = acc + b2s[c];
}

extern "C" void kernel_launch(void* const* d_in, const int* in_sizes, int n_in,
                              void* d_out, int out_size, void* d_ws, size_t ws_size,
                              hipStream_t stream) {
    const float* x     = (const float*)d_in[0];
    const int*   ei    = (const int*)d_in[1];
    const float* W1    = (const float*)d_in[2];
    const float* b1    = (const float*)d_in[3];
    const float* W2    = (const float*)d_in[4];
    const float* b2    = (const float*)d_in[5];
    const float* Wl    = (const float*)d_in[6];
    const float* Wr    = (const float*)d_in[7];
    const float* eps   = (const float*)d_in[8];
    const float* Wsh   = (const float*)d_in[9];
    const float* Wwt   = (const float*)d_in[10];
    float* out = (float*)d_out;
    const int* row = ei;        // edge_index[0]
    const int* col = ei + E2;   // edge_index[1]

    char* pc = (char*)d_ws;
    float* xc     = (float*)pc;          pc += (size_t)NN * 96 * 4;
    uint2* meta   = (uint2*)pc;          pc += (size_t)E2 * 8;
    unsigned* yA0 = (unsigned*)pc;       pc += (size_t)NN * 32 * 4;
    unsigned* yA1 = (unsigned*)pc;       pc += (size_t)NN * 32 * 4;
    unsigned short* yB0 = (unsigned short*)pc; pc += (size_t)NN * 32 * 2;
    unsigned short* yB1 = (unsigned short*)pc; pc += (size_t)NN * 32 * 2;
    pc = (char*)(((size_t)pc + 15) & ~(size_t)15);
    float4* proj  = (float4*)pc;         pc += (size_t)NN * 16;
    float* deg0   = (float*)pc;          pc += (size_t)NN * 4;
    float* deg1   = (float*)pc;          pc += (size_t)NN * 4;
    float* Wl_n   = (float*)pc;          pc += 32 * 4;
    float* Wr_n   = (float*)pc;          pc += 2048 * 4;
    int* cnt      = (int*)pc;            pc += (size_t)NN * 4;
    int* start    = (int*)pc;            pc += (size_t)NN * 4;
    int* fill     = (int*)pc;            pc += (size_t)NN * 4;
    int* eslot    = (int*)pc;            pc += (size_t)E2 * 4;
    int* gtotal   = (int*)pc;            pc += 4;

    // 8 dispatches total
    k_setup<<<NCHUNK + 2, 256, 0, stream>>>(Wl, Wr, Wl_n, Wr_n, cnt, fill, deg0, gtotal);
    k_gemm<128, 96, 48, true, true><<<1024, 256, 0, stream>>>(x, W1, b1, xc, row, cnt);
    k_scan<<<NCHUNK, 256, 0, stream>>>(cnt, start, gtotal);
    k_filly8<<<NGROUPS + EB, 256, 0, stream>>>(xc, Wl_n, Wr_n, Wsh, Wwt,
                                               yA0, yB0, proj, row, start, fill, eslot);
    k_coef<<<(E0 + 255) / 256, 256, 0, stream>>>(row, col, eslot, proj, meta, deg0);
    k_gatherY<<<NGROUPS, 256, 0, stream>>>(start, cnt, meta, deg0, yA0, yB0, eps, xc,
                                           Wl_n + 9, Wr_n + 1024, Wsh, Wwt, yA1, yB1, proj, deg1);
    k_coef<<<(E0 + 255) / 256, 256, 0, stream>>>(row, col, eslot, proj, meta, deg1);
    k_gatherF<<<NGROUPS, 256, 0, stream>>>(start, cnt, meta, deg1, yA1, yB1, eps, xc,
                                           W2, b2, out);
}

// Round 5
// 316.920 us; speedup vs baseline: 1.0801x; 1.0801x over previous
//
#include <hip/hip_runtime.h>

#define NN 50000
#define E0 200000
#define E2 400000
#define NGROUPS ((NN + 7) / 8)      // 6250 (×8 = 50000 exactly)
#define NCHUNK  ((NN + 255) / 256)  // 196
#define NTILES  ((NN + 63) / 64)    // 782
#define EB      ((E2 + 255) / 256)  // 1563

typedef __attribute__((ext_vector_type(8))) short short8;
typedef __attribute__((ext_vector_type(4))) float f32x4;

__device__ __forceinline__ float eluf(float x) { return x > 0.0f ? x : expm1f(x); }
__device__ __forceinline__ float fsig(float x) { return 1.0f / (1.0f + __expf(-x)); }
__device__ __forceinline__ float ftanh(float x) {
    float e = __expf(-2.0f * x);
    return (1.0f - e) / (1.0f + e);
}
__device__ __forceinline__ unsigned rne_bf16(float x) {
    unsigned u = __float_as_uint(x);
    return (u + 0x7fffu + ((u >> 16) & 1u)) >> 16;
}

// ---------------- single-wave spectral norm: lane r holds u[r]; matvecs via shfl broadcast;
// LDS stride-33 is bank-conflict-free for BOTH row and column access; no __syncthreads in loop.
__device__ __forceinline__ void spectral_block(int l, const float* __restrict__ Wl_in,
                                               const float* __restrict__ Wr_in,
                                               float* __restrict__ Wl_out, float* __restrict__ Wr_out) {
    __shared__ float W[32 * 33];
    __shared__ float sscal;
    int t = threadIdx.x;
    for (int i = t; i < 1024; i += 256) W[(i >> 5) * 33 + (i & 31)] = Wr_in[l * 1024 + i];
    __syncthreads();
    if (t < 32) {
        float u = 0.17677669529663688f;     // 1/sqrt(32), lane r holds u[r]
        for (int it = 0; it < 20; ++it) {
            float v = 0.f;                   // v[c] = sum_r W[r][c] * u[r]  (lane c)
#pragma unroll 8
            for (int r = 0; r < 32; ++r) v = fmaf(W[r * 33 + t], __shfl(u, r, 32), v);
            float s = v * v;
#pragma unroll
            for (int off = 16; off; off >>= 1) s += __shfl_xor(s, off, 32);
            v *= 1.0f / (sqrtf(s) + 1e-12f);
            float u2 = 0.f;                  // u2[r] = sum_c W[r][c] * v[c]  (lane r)
#pragma unroll 8
            for (int c = 0; c < 32; ++c) u2 = fmaf(W[t * 33 + c], __shfl(v, c, 32), u2);
            s = u2 * u2;
#pragma unroll
            for (int off = 16; off; off >>= 1) s += __shfl_xor(s, off, 32);
            u = u2 * (1.0f / (sqrtf(s) + 1e-12f));
        }
        // sigma: v = W^T u (final); s = ||v||^2 ; 1/sigma = (sqrt(s)+1e-12)/s  (matches ref)
        float v = 0.f;
#pragma unroll 8
        for (int r = 0; r < 32; ++r) v = fmaf(W[r * 33 + t], __shfl(u, r, 32), v);
        float s = v * v;
#pragma unroll
        for (int off = 16; off; off >>= 1) s += __shfl_xor(s, off, 32);
        if (t == 0) sscal = (sqrtf(s) + 1e-12f) / s;
    } else if (t == 64) {                    // Wl 3x3 power iteration on wave 1, concurrent
        float M[9];
        for (int i = 0; i < 9; ++i) M[i] = Wl_in[l * 9 + i];
        float u[3] = {0.5773502691896258f, 0.5773502691896258f, 0.5773502691896258f};
        float v[3], u2[3];
        for (int it = 0; it < 20; ++it) {
            float s = 0;
            for (int c = 0; c < 3; ++c) { v[c] = M[c] * u[0] + M[3 + c] * u[1] + M[6 + c] * u[2]; s += v[c] * v[c]; }
            float inv = 1.0f / (sqrtf(s) + 1e-12f);
            for (int c = 0; c < 3; ++c) v[c] *= inv;
            s = 0;
            for (int r = 0; r < 3; ++r) { u2[r] = M[r * 3] * v[0] + M[r * 3 + 1] * v[1] + M[r * 3 + 2] * v[2]; s += u2[r] * u2[r]; }
            inv = 1.0f / (sqrtf(s) + 1e-12f);
            for (int r = 0; r < 3; ++r) u[r] = u2[r] * inv;
        }
        float s = 0;
        for (int c = 0; c < 3; ++c) { v[c] = M[c] * u[0] + M[3 + c] * u[1] + M[6 + c] * u[2]; s += v[c] * v[c]; }
        float inv = (sqrtf(s) + 1e-12f) / s;
        for (int i = 0; i < 9; ++i) Wl_out[l * 9 + i] = M[i] * inv;
    }
    __syncthreads();
    float invs = sscal;
    for (int i = t; i < 1024; i += 256) Wr_out[l * 1024 + i] = W[(i >> 5) * 33 + (i & 31)] * invs;
}

// ---------------- setup: blocks 0,1 = spectral norm per layer; rest zero counters
__global__ __launch_bounds__(256) void k_setup(const float* __restrict__ Wl_in, const float* __restrict__ Wr_in,
                                               float* __restrict__ Wl_out, float* __restrict__ Wr_out,
                                               int* __restrict__ cnt, int* __restrict__ fill,
                                               float* __restrict__ deg0, int* __restrict__ gtotal) {
    if (blockIdx.x < 2) {
        spectral_block((int)blockIdx.x, Wl_in, Wr_in, Wl_out, Wr_out);
        return;
    }
    int i = (blockIdx.x - 2) * 256 + threadIdx.x;
    if (i == 0) *gtotal = 0;
    if (i < NN) { cnt[i] = 0; fill[i] = 0; deg0[i] = 0.0f; }
}

// ---------------- MFMA GEMM: multi-tile grid-stride + N column-split
template<int K, int N, int NH, bool ELU, bool HIST>
__global__ __launch_bounds__(256) void k_gemm(const float* __restrict__ X,
                                              const float* __restrict__ W,
                                              const float* __restrict__ bias,
                                              float* __restrict__ out,
                                              const int* __restrict__ row, int* __restrict__ cnt) {
    constexpr int KP = K + 8;
    constexpr int NT = NH / 16;
    constexpr int KS = K / 32;
    constexpr int NHALVES = N / NH;
    __shared__ __align__(16) unsigned short whi[NH * KP];
    __shared__ __align__(16) unsigned short wlo[NH * KP];
    int tid = threadIdx.x;
    if (HIST) {   // independent atomics first; latency hides behind GEMM
        for (int e = blockIdx.x * 256 + tid; e < E2; e += gridDim.x * 256)
            atomicAdd(&cnt[row[e]], 1);
    }
    const int ch = blockIdx.x % NHALVES;
    const int tstream = blockIdx.x / NHALVES;
    const int nstreams = gridDim.x / NHALVES;
    for (int i = tid; i < NH * K; i += 256) {
        float v = W[ch * NH * K + i];
        int r = i / K, c = i % K;
        unsigned h = rne_bf16(v);
        whi[r * KP + c] = (unsigned short)h;
        wlo[r * KP + c] = (unsigned short)rne_bf16(v - __uint_as_float(h << 16));
    }
    __syncthreads();
    int wave = tid >> 6, lane = tid & 63;
    int quad = lane >> 4, r16 = lane & 15;
    for (int t = tstream; t < NTILES; t += nstreams) {
        long m = (long)t * 64 + wave * 16 + r16;
        long mc = m < NN ? m : (NN - 1);
        const float* xrow = X + mc * K + quad * 8;
        short8 ah[KS], al[KS];
#pragma unroll
        for (int ks = 0; ks < KS; ++ks) {
            const float4* xp = (const float4*)(xrow + ks * 32);
            float4 p0 = xp[0], p1 = xp[1];
            float xv[8] = {p0.x, p0.y, p0.z, p0.w, p1.x, p1.y, p1.z, p1.w};
#pragma unroll
            for (int j = 0; j < 8; ++j) {
                unsigned h = rne_bf16(xv[j]);
                ah[ks][j] = (short)h;
                al[ks][j] = (short)rne_bf16(xv[j] - __uint_as_float(h << 16));
            }
        }
        long mbase = (long)t * 64 + wave * 16 + quad * 4;
#pragma unroll
        for (int tt = 0; tt < NT; ++tt) {
            f32x4 acc = (f32x4){0.f, 0.f, 0.f, 0.f};
#pragma unroll
            for (int ks = 0; ks < KS; ++ks) {
                int ro = (tt * 16 + r16) * KP + ks * 32 + quad * 8;
                short8 bh = *(const short8*)&whi[ro];
                short8 bl = *(const short8*)&wlo[ro];
                acc = __builtin_amdgcn_mfma_f32_16x16x32_bf16(ah[ks], bh, acc, 0, 0, 0);
                acc = __builtin_amdgcn_mfma_f32_16x16x32_bf16(al[ks], bh, acc, 0, 0, 0);
                acc = __builtin_amdgcn_mfma_f32_16x16x32_bf16(ah[ks], bl, acc, 0, 0, 0);
            }
            // C/D layout: col = lane&15, row = quad*4 + reg [m89-verified]
            int coln = ch * NH + tt * 16 + r16;
            float b = bias[coln];
#pragma unroll
            for (int rr = 0; rr < 4; ++rr) {
                long mm = mbase + rr;
                if (mm < NN) {
                    float v = acc[rr] + b;
                    if (ELU) v = eluf(v);
                    out[mm * N + coln] = v;
                }
            }
        }
    }
}

// ---------------- single-pass scan: local prefix + atomic grid offset -> absolute start
__global__ __launch_bounds__(256) void k_scan(const int* __restrict__ cnt, int* __restrict__ start,
                                              int* __restrict__ gtotal) {
    __shared__ int s[256];
    __shared__ int soff;
    int b = blockIdx.x, t = threadIdx.x;
    int i = b * 256 + t;
    int v = (i < NN) ? cnt[i] : 0;
    s[t] = v;
    __syncthreads();
    for (int off = 1; off < 256; off <<= 1) {
        int add = (t >= off) ? s[t - off] : 0;
        __syncthreads();
        s[t] += add;
        __syncthreads();
    }
    if (t == 255) soff = atomicAdd(gtotal, s[255]);   // chunk order nondeterministic; slots stay disjoint
    __syncthreads();
    if (i < NN) start[i] = s[t] - v + soff;
}

// ---------------- fused: blocks [0,NGROUPS) = y8 layer 0 ; [NGROUPS, +EB) = CSR fill
__global__ __launch_bounds__(256) void k_filly8(const float* __restrict__ xc,
                                                const float* __restrict__ Wl, const float* __restrict__ Wr,
                                                const float* __restrict__ Wsh, const float* __restrict__ Wwt,
                                                unsigned* __restrict__ yA, unsigned short* __restrict__ yB,
                                                float4* __restrict__ proj,
                                                const int* __restrict__ row, const int* __restrict__ start,
                                                int* __restrict__ fill, int* __restrict__ eslot) {
    int tid = threadIdx.x;
    if (blockIdx.x >= NGROUPS) {   // CSR fill branch
        int e = (blockIdx.x - NGROUPS) * 256 + tid;
        if (e < E2) {
            int u = row[e];
            eslot[e] = start[u] + atomicAdd(&fill[u], 1);
        }
        return;
    }
    __shared__ float wrs[32 * 33];
    __shared__ float wls[9];
    __shared__ float xcs[8][96];
    __shared__ float ws1[192], wt[192];
    int n0 = blockIdx.x * 8;
    for (int i = tid; i < 1024; i += 256) wrs[(i >> 5) * 33 + (i & 31)] = Wr[i];
    if (tid < 9) wls[tid] = Wl[tid];
    if (tid < 192) {
        ws1[tid] = Wsh[192 + tid];   // layer 0, row 1 of W_sheaf (only row surviving Cayley, D=2)
        wt[tid]  = Wwt[tid];
    }
    for (int i = tid; i < 192; i += 256) {
        int nd = i / 24, of = (i % 24) * 4;
        *(float4*)&xcs[nd][of] = *(const float4*)&xc[(n0 + nd) * 96 + of];
    }
    __syncthreads();
    int node = tid >> 5, c = tid & 31;
    int n = n0 + node;
    float a1 = 0, a2 = 0, a3 = 0, a4 = 0;
#pragma unroll
    for (int j = 0; j < 3; ++j) {
        int k = j * 32 + c;
        float xv = xcs[node][k];
        a1 = fmaf(xv, ws1[k], a1);
        a2 = fmaf(xv, ws1[96 + k], a2);
        a3 = fmaf(xv, wt[k], a3);
        a4 = fmaf(xv, wt[96 + k], a4);
    }
#pragma unroll
    for (int off = 16; off; off >>= 1) {
        a1 += __shfl_xor(a1, off);
        a2 += __shfl_xor(a2, off);
        a3 += __shfl_xor(a3, off);
        a4 += __shfl_xor(a4, off);
    }
    if (c == 0) proj[n] = make_float4(a1, a2, a3, a4);   // {aR, aC, wR, wC}
    {
        float t0 = 0, t1 = 0, t2 = 0;
        const float* wr = &wrs[c * 33];
        const float* xr = xcs[node];
#pragma unroll
        for (int h = 0; h < 32; ++h) {
            float w = wr[h];
            t0 = fmaf(xr[h], w, t0);
            t1 = fmaf(xr[32 + h], w, t1);
            t2 = fmaf(xr[64 + h], w, t2);
        }
        float o0 = wls[0] * t0 + wls[1] * t1 + wls[2] * t2;
        float o1 = wls[3] * t0 + wls[4] * t1 + wls[5] * t2;
        float o2 = wls[6] * t0 + wls[7] * t1 + wls[8] * t2;
        yA[n * 32 + c] = rne_bf16(o0) | (rne_bf16(o1) << 16);
        yB[n * 32 + c] = (unsigned short)rne_bf16(o2);
    }
}

// ---------------- per-edge coefficients, 8B packed meta + degree
__global__ __launch_bounds__(256) void k_coef(const int* __restrict__ row, const int* __restrict__ col,
                                              const int* __restrict__ eslot,
                                              const float4* __restrict__ proj,
                                              uint2* __restrict__ meta, float* __restrict__ deg) {
    int e = blockIdx.x * 256 + threadIdx.x;
    if (e >= E0) return;
    int u = row[e], v = col[e];
    float4 pu = proj[u], pv = proj[v];
    float a_e = ftanh(pu.x + pv.y);
    float a_r = ftanh(pv.x + pu.y);
    float wd_e = fsig(pu.z + pv.w);
    float wd_r = fsig(pv.z + pu.w);
    float w = wd_e * wd_r;
    float w2 = w * w;
    float ie = 1.0f / (1.0f + a_e * a_e), ir = 1.0f / (1.0f + a_r * a_r);
    float ce = (1.0f - a_e * a_e) * ie, se = 2.0f * a_e * ie;
    float cr = (1.0f - a_r * a_r) * ir, sr = 2.0f * a_r * ir;
    float C = ce * cr + se * sr;   // T_e = Q_e^T Q_rev ; T_rev = T_e^T -> (C,-S)
    float S = ce * sr - se * cr;
    unsigned cb = rne_bf16(C), sb = rne_bf16(S), wb = rne_bf16(w2);
    meta[eslot[e]]      = make_uint2(cb | (sb << 16), (unsigned)v | (wb << 16));
    meta[eslot[e + E0]] = make_uint2(cb | ((sb ^ 0x8000u) << 16), (unsigned)u | (wb << 16));
    atomicAdd(&deg[u], w2);
    atomicAdd(&deg[v], w2);
}

// ---------------- gather body (2 nodes/wave, 32-lane halves)
// Coefficients staged in LDS float4 (1 ds_write_b128 per edge), then the j-loop reads
// them via ONE same-address ds_read_b128 broadcast per edge — replaces 4 ds_bpermute
// (__shfl) per edge. DS-pipe ops per 32-edge batch: 129 -> 33 (r4 lesson: DS issue
// count is the scarce resource in this latency-bound gather). Same-half-warp
// write->read needs no barrier (intra-wave LDS ordering).
__device__ __forceinline__ void gather_accum(int s0, int ec, int c,
                                             const uint2* __restrict__ meta,
                                             const float* __restrict__ deg, float du,
                                             const unsigned* __restrict__ yA,
                                             const unsigned short* __restrict__ yB,
                                             float4* __restrict__ ecoef,   // this node's 32-slot LDS
                                             float& acc0, float& acc1, float& acc2) {
    for (int bs = 0; bs < ec; bs += 32) {
        int nb2 = min(32, ec - bs);
        if (c < nb2) {
            uint2 mt = meta[s0 + bs + c];
            int vj = (int)(mt.y & 0xffffu);
            float w2 = __uint_as_float(mt.y & 0xffff0000u);
            float Cv = __uint_as_float(mt.x << 16);
            float Sv = __uint_as_float(mt.x & 0xffff0000u);
            float dv = deg[vj];
            float dvi = dv > 0.0f ? rsqrtf(fmaxf(dv, 1e-30f)) : 0.0f;
            float cnl = w2 * du * dvi;
            ecoef[c] = make_float4(cnl * Cv, cnl * Sv, cnl, __int_as_float(vj));
        }
        int j4 = nb2 & ~3;
        int j = 0;
        for (; j < j4; j += 4) {
#pragma unroll
            for (int jj = 0; jj < 4; ++jj) {
                float4 e = ecoef[j + jj];          // same-addr broadcast, conflict-free
                int v = __float_as_int(e.w);
                unsigned ua = yA[v * 32 + c];
                unsigned ub = (unsigned)yB[v * 32 + c];
                float y0 = __uint_as_float(ua << 16);
                float y1 = __uint_as_float(ua & 0xffff0000u);
                float y2 = __uint_as_float(ub << 16);
                acc0 = fmaf(e.x, y0, acc0);
                acc0 = fmaf(-e.y, y1, acc0);
                acc1 = fmaf(e.y, y0, acc1);
                acc1 = fmaf(e.x, y1, acc1);
                acc2 = fmaf(e.z, y2, acc2);
            }
        }
        for (; j < nb2; ++j) {
            float4 e = ecoef[j];
            int v = __float_as_int(e.w);
            unsigned ua = yA[v * 32 + c];
            unsigned ub = (unsigned)yB[v * 32 + c];
            float y0 = __uint_as_float(ua << 16);
            float y1 = __uint_as_float(ua & 0xffff0000u);
            float y2 = __uint_as_float(ub << 16);
            acc0 = fmaf(e.x, y0, acc0);
            acc0 = fmaf(-e.y, y1, acc0);
            acc1 = fmaf(e.y, y0, acc1);
            acc1 = fmaf(e.x, y1, acc1);
            acc2 = fmaf(e.z, y2, acc2);
        }
    }
}

// ---------------- gather layer 0 + residual + FUSED y8 layer 1 (8 nodes/block, 2/wave)
__global__ __launch_bounds__(256) void k_gatherY(const int* __restrict__ start,
                                                 const int* __restrict__ cnt,
                                                 const uint2* __restrict__ meta,
                                                 const float* __restrict__ deg0,
                                                 const unsigned* __restrict__ yA0,
                                                 const unsigned short* __restrict__ yB0,
                                                 const float* __restrict__ eps,
                                                 float* __restrict__ xc,
                                                 const float* __restrict__ Wl, const float* __restrict__ Wr,
                                                 const float* __restrict__ Wsh, const float* __restrict__ Wwt,
                                                 unsigned* __restrict__ yA1, unsigned short* __restrict__ yB1,
                                                 float4* __restrict__ proj, float* __restrict__ deg1) {
    __shared__ float wrs[32 * 33];
    __shared__ float wls[9];
    __shared__ float xcs[8][96];
    __shared__ float ws1[192], wt[192];
    __shared__ float4 ecoef[8][32];
    int tid = threadIdx.x;
    int node = tid >> 5, c = tid & 31;
    int n = blockIdx.x * 8 + node;                 // NGROUPS*8 == NN: always in range
    // issue scalar per-node loads before staging so they overlap it
    int s0 = start[n], ec = cnt[n];
    float dn = deg0[n];
    for (int i = tid; i < 1024; i += 256) wrs[(i >> 5) * 33 + (i & 31)] = Wr[i];
    if (tid < 9) wls[tid] = Wl[tid];
    if (tid < 192) {
        ws1[tid] = Wsh[(1 * 3 + 1) * 192 + tid];   // layer 1 sheaf row
        wt[tid]  = Wwt[1 * 192 + tid];
    }
    __syncthreads();                               // weight staging visible to all waves
    float du = dn > 0.0f ? rsqrtf(fmaxf(dn, 1e-30f)) : 0.0f;
    float acc0 = 0, acc1 = 0, acc2 = 0;
    gather_accum(s0, ec, c, meta, deg0, du, yA0, yB0, ecoef[node], acc0, acc1, acc2);
    float diag = dn > 0.0f ? 1.0f : 0.0f;
    unsigned ua = yA0[n * 32 + c];
    unsigned ub = (unsigned)yB0[n * 32 + c];
    float oy0 = __uint_as_float(ua << 16);
    float oy1 = __uint_as_float(ua & 0xffff0000u);
    float oy2 = __uint_as_float(ub << 16);
    float c0 = 1.0f + tanhf(eps[0]);
    float c1 = 1.0f + tanhf(eps[1]);
    float c2 = 1.0f + tanhf(eps[2]);
    int base = n * 96 + c;
    float nx0 = c0 * xc[base]      - eluf(diag * oy0 - acc0);
    float nx1 = c1 * xc[base + 32] - eluf(diag * oy1 - acc1);
    float nx2 = c2 * xc[base + 64] - eluf(diag * oy2 - acc2);
    xc[base] = nx0; xc[base + 32] = nx1; xc[base + 64] = nx2;
    if (c == 0) deg1[n] = 0.0f;                    // zero next layer's degree
    xcs[node][c] = nx0; xcs[node][32 + c] = nx1; xcs[node][64 + c] = nx2;
    // NO __syncthreads: layer-1 epilogue reads only xcs[node], written by this same
    // half-warp (intra-wave LDS ordering); waves stay decoupled from slow gathers.
    // ---- layer-1 projections (own channels in registers) ----
    float a1 = nx0 * ws1[c] + nx1 * ws1[32 + c] + nx2 * ws1[64 + c];
    float a2 = nx0 * ws1[96 + c] + nx1 * ws1[128 + c] + nx2 * ws1[160 + c];
    float a3 = nx0 * wt[c] + nx1 * wt[32 + c] + nx2 * wt[64 + c];
    float a4 = nx0 * wt[96 + c] + nx1 * wt[128 + c] + nx2 * wt[160 + c];
#pragma unroll
    for (int off = 16; off; off >>= 1) {
        a1 += __shfl_xor(a1, off);
        a2 += __shfl_xor(a2, off);
        a3 += __shfl_xor(a3, off);
        a4 += __shfl_xor(a4, off);
    }
    if (c == 0) proj[n] = make_float4(a1, a2, a3, a4);
    // ---- layer-1 y ----
    {
        float t0 = 0, t1 = 0, t2 = 0;
        const float* wr = &wrs[c * 33];
        const float* xr = xcs[node];
#pragma unroll
        for (int h = 0; h < 32; ++h) {
            float w = wr[h];
            t0 = fmaf(xr[h], w, t0);
            t1 = fmaf(xr[32 + h], w, t1);
            t2 = fmaf(xr[64 + h], w, t2);
        }
        float o0 = wls[0] * t0 + wls[1] * t1 + wls[2] * t2;
        float o1 = wls[3] * t0 + wls[4] * t1 + wls[5] * t2;
        float o2 = wls[6] * t0 + wls[7] * t1 + wls[8] * t2;
        yA1[n * 32 + c] = rne_bf16(o0) | (rne_bf16(o1) << 16);
        yB1[n * 32 + c] = (unsigned short)rne_bf16(o2);
    }
}

// ---------------- plain gather + residual (layer 1)
__global__ __launch_bounds__(256) void k_gather(const int* __restrict__ start,
                                                const int* __restrict__ cnt,
                                                const uint2* __restrict__ meta,
                                                const float* __restrict__ deg,
                                                const unsigned* __restrict__ yA,
                                                const unsigned short* __restrict__ yB,
                                                const float* __restrict__ eps,
                                                int layer, float* __restrict__ xc) {
    __shared__ float4 ecoef[8][32];
    int tid = threadIdx.x;
    int node = tid >> 5, c = tid & 31;
    int n = blockIdx.x * 8 + node;
    if (n >= NN) return;
    int s0 = start[n], ec = cnt[n];
    float dn = deg[n];
    float du = dn > 0.0f ? rsqrtf(fmaxf(dn, 1e-30f)) : 0.0f;
    float acc0 = 0, acc1 = 0, acc2 = 0;
    gather_accum(s0, ec, c, meta, deg, du, yA, yB, ecoef[node], acc0, acc1, acc2);
    float diag = dn > 0.0f ? 1.0f : 0.0f;
    unsigned ua = yA[n * 32 + c];
    unsigned ub = (unsigned)yB[n * 32 + c];
    float oy0 = __uint_as_float(ua << 16);
    float oy1 = __uint_as_float(ua & 0xffff0000u);
    float oy2 = __uint_as_float(ub << 16);
    float c0 = 1.0f + tanhf(eps[layer * 3 + 0]);
    float c1 = 1.0f + tanhf(eps[layer * 3 + 1]);
    float c2 = 1.0f + tanhf(eps[layer * 3 + 2]);
    int base = n * 96 + c;
    float z0 = eluf(diag * oy0 - acc0);
    float z1 = eluf(diag * oy1 - acc1);
    float z2 = eluf(diag * oy2 - acc2);
    xc[base]      = c0 * xc[base]      - z0;
    xc[base + 32] = c1 * xc[base + 32] - z1;
    xc[base + 64] = c2 * xc[base + 64] - z2;
}

extern "C" void kernel_launch(void* const* d_in, const int* in_sizes, int n_in,
                              void* d_out, int out_size, void* d_ws, size_t ws_size,
                              hipStream_t stream) {
    const float* x     = (const float*)d_in[0];
    const int*   ei    = (const int*)d_in[1];
    const float* W1    = (const float*)d_in[2];
    const float* b1    = (const float*)d_in[3];
    const float* W2    = (const float*)d_in[4];
    const float* b2    = (const float*)d_in[5];
    const float* Wl    = (const float*)d_in[6];
    const float* Wr    = (const float*)d_in[7];
    const float* eps   = (const float*)d_in[8];
    const float* Wsh   = (const float*)d_in[9];
    const float* Wwt   = (const float*)d_in[10];
    float* out = (float*)d_out;
    const int* row = ei;        // edge_index[0]
    const int* col = ei + E2;   // edge_index[1]

    char* pc = (char*)d_ws;
    float* xc     = (float*)pc;          pc += (size_t)NN * 96 * 4;
    uint2* meta   = (uint2*)pc;          pc += (size_t)E2 * 8;
    unsigned* yA0 = (unsigned*)pc;       pc += (size_t)NN * 32 * 4;
    unsigned* yA1 = (unsigned*)pc;       pc += (size_t)NN * 32 * 4;
    unsigned short* yB0 = (unsigned short*)pc; pc += (size_t)NN * 32 * 2;
    unsigned short* yB1 = (unsigned short*)pc; pc += (size_t)NN * 32 * 2;
    pc = (char*)(((size_t)pc + 15) & ~(size_t)15);
    float4* proj  = (float4*)pc;         pc += (size_t)NN * 16;
    float* deg0   = (float*)pc;          pc += (size_t)NN * 4;
    float* deg1   = (float*)pc;          pc += (size_t)NN * 4;
    float* Wl_n   = (float*)pc;          pc += 32 * 4;
    float* Wr_n   = (float*)pc;          pc += 2048 * 4;
    int* cnt      = (int*)pc;            pc += (size_t)NN * 4;
    int* start    = (int*)pc;            pc += (size_t)NN * 4;
    int* fill     = (int*)pc;            pc += (size_t)NN * 4;
    int* eslot    = (int*)pc;            pc += (size_t)E2 * 4;
    int* gtotal   = (int*)pc;            pc += 4;

    // 9 dispatches total
    k_setup<<<NCHUNK + 2, 256, 0, stream>>>(Wl, Wr, Wl_n, Wr_n, cnt, fill, deg0, gtotal);
    k_gemm<128, 96, 48, true, true><<<1024, 256, 0, stream>>>(x, W1, b1, xc, row, cnt);
    k_scan<<<NCHUNK, 256, 0, stream>>>(cnt, start, gtotal);
    k_filly8<<<NGROUPS + EB, 256, 0, stream>>>(xc, Wl_n, Wr_n, Wsh, Wwt,
                                               yA0, yB0, proj, row, start, fill, eslot);
    k_coef<<<(E0 + 255) / 256, 256, 0, stream>>>(row, col, eslot, proj, meta, deg0);
    k_gatherY<<<NGROUPS, 256, 0, stream>>>(start, cnt, meta, deg0, yA0, yB0, eps, xc,
                                           Wl_n + 9, Wr_n + 1024, Wsh, Wwt, yA1, yB1, proj, deg1);
    k_coef<<<(E0 + 255) / 256, 256, 0, stream>>>(row, col, eslot, proj, meta, deg1);
    k_gather<<<NGROUPS, 256, 0, stream>>>(start, cnt, meta, deg1, yA1, yB1, eps, 1, xc);
    k_gemm<96, 32, 32, false, false><<<782, 256, 0, stream>>>(xc, W2, b2, out, nullptr, nullptr);
}

// Round 7
// 309.448 us; speedup vs baseline: 1.1062x; 1.0241x over previous
//
#include <hip/hip_runtime.h>

#define NN 50000
#define E0 200000
#define E2 400000
#define NGROUPS ((NN + 7) / 8)      // 6250 (×8 = 50000 exactly)
#define NCHUNK  ((NN + 255) / 256)  // 196
#define NTILES  ((NN + 63) / 64)    // 782
#define EB      ((E2 + 255) / 256)  // 1563

typedef __attribute__((ext_vector_type(8))) short short8;
typedef __attribute__((ext_vector_type(4))) float f32x4;

__device__ __forceinline__ float eluf(float x) { return x > 0.0f ? x : expm1f(x); }
__device__ __forceinline__ float fsig(float x) { return 1.0f / (1.0f + __expf(-x)); }
__device__ __forceinline__ float ftanh(float x) {
    float e = __expf(-2.0f * x);
    return (1.0f - e) / (1.0f + e);
}
__device__ __forceinline__ unsigned rne_bf16(float x) {
    unsigned u = __float_as_uint(x);
    return (u + 0x7fffu + ((u >> 16) & 1u)) >> 16;
}

// ---------------- single-wave spectral norm + (l==0) build M0 = [kron(Wl,Wr); proj rows; 0-pad]
// lane r holds u[r]; matvecs via shfl broadcast; stride-33 LDS conflict-free both ways.
__device__ __forceinline__ void spectral_block(int l, const float* __restrict__ Wl_in,
                                               const float* __restrict__ Wr_in,
                                               float* __restrict__ Wl_out, float* __restrict__ Wr_out,
                                               const float* __restrict__ Wsh, const float* __restrict__ Wwt,
                                               float* __restrict__ M0) {
    __shared__ float W[32 * 33];
    __shared__ float sscal;
    __shared__ float wl_s[9];
    int t = threadIdx.x;
    for (int i = t; i < 1024; i += 256) W[(i >> 5) * 33 + (i & 31)] = Wr_in[l * 1024 + i];
    __syncthreads();
    if (t < 32) {
        float u = 0.17677669529663688f;     // 1/sqrt(32), lane r holds u[r]
        for (int it = 0; it < 20; ++it) {
            float v = 0.f;                   // v[c] = sum_r W[r][c] * u[r]  (lane c)
#pragma unroll 8
            for (int r = 0; r < 32; ++r) v = fmaf(W[r * 33 + t], __shfl(u, r, 32), v);
            float s = v * v;
#pragma unroll
            for (int off = 16; off; off >>= 1) s += __shfl_xor(s, off, 32);
            v *= 1.0f / (sqrtf(s) + 1e-12f);
            float u2 = 0.f;                  // u2[r] = sum_c W[r][c] * v[c]  (lane r)
#pragma unroll 8
            for (int c = 0; c < 32; ++c) u2 = fmaf(W[t * 33 + c], __shfl(v, c, 32), u2);
            s = u2 * u2;
#pragma unroll
            for (int off = 16; off; off >>= 1) s += __shfl_xor(s, off, 32);
            u = u2 * (1.0f / (sqrtf(s) + 1e-12f));
        }
        // sigma: v = W^T u (final); s = ||v||^2 ; 1/sigma = (sqrt(s)+1e-12)/s  (matches ref)
        float v = 0.f;
#pragma unroll 8
        for (int r = 0; r < 32; ++r) v = fmaf(W[r * 33 + t], __shfl(u, r, 32), v);
        float s = v * v;
#pragma unroll
        for (int off = 16; off; off >>= 1) s += __shfl_xor(s, off, 32);
        if (t == 0) sscal = (sqrtf(s) + 1e-12f) / s;
    } else if (t == 64) {                    // Wl 3x3 power iteration on wave 1, concurrent
        float M[9];
        for (int i = 0; i < 9; ++i) M[i] = Wl_in[l * 9 + i];
        float u[3] = {0.5773502691896258f, 0.5773502691896258f, 0.5773502691896258f};
        float v[3], u2[3];
        for (int it = 0; it < 20; ++it) {
            float s = 0;
            for (int c = 0; c < 3; ++c) { v[c] = M[c] * u[0] + M[3 + c] * u[1] + M[6 + c] * u[2]; s += v[c] * v[c]; }
            float inv = 1.0f / (sqrtf(s) + 1e-12f);
            for (int c = 0; c < 3; ++c) v[c] *= inv;
            s = 0;
            for (int r = 0; r < 3; ++r) { u2[r] = M[r * 3] * v[0] + M[r * 3 + 1] * v[1] + M[r * 3 + 2] * v[2]; s += u2[r] * u2[r]; }
            inv = 1.0f / (sqrtf(s) + 1e-12f);
            for (int r = 0; r < 3; ++r) u[r] = u2[r] * inv;
        }
        float s = 0;
        for (int c = 0; c < 3; ++c) { v[c] = M[c] * u[0] + M[3 + c] * u[1] + M[6 + c] * u[2]; s += v[c] * v[c]; }
        float inv = (sqrtf(s) + 1e-12f) / s;
        for (int i = 0; i < 9; ++i) { float w = M[i] * inv; Wl_out[l * 9 + i] = w; wl_s[i] = w; }
    }
    __syncthreads();
    float invs = sscal;
    for (int i = t; i < 1024; i += 256) Wr_out[l * 1024 + i] = W[(i >> 5) * 33 + (i & 31)] * invs;
    if (l == 0) {
        // rows 0..95: kron(Wl, Wr_scaled): M0[e*32+cc][f*32+h] = Wl[e,f]*Wr[cc,h]
        for (int i = t; i < 96 * 96; i += 256) {
            int yc = i / 96, k = i % 96;
            int e = yc >> 5, cc = yc & 31, f = k >> 5, h = k & 31;
            M0[yc * 96 + k] = wl_s[e * 3 + f] * W[cc * 33 + h] * invs;
        }
        // rows 96..99: [ws1 row0; ws1 row1; wt row0; wt row1] (layer 0)
        for (int i = t; i < 4 * 96; i += 256) {
            int r = i / 96, k = i % 96;
            float v = (r < 2) ? Wsh[192 + r * 96 + k] : Wwt[(r - 2) * 96 + k];
            M0[(96 + r) * 96 + k] = v;
        }
        // rows 100..111: zero pad
        for (int i = t; i < 12 * 96; i += 256) M0[100 * 96 + i] = 0.f;
    }
}

// ---------------- setup: blocks 0,1 = spectral norm per layer (+M0); rest zero counters
__global__ __launch_bounds__(256) void k_setup(const float* __restrict__ Wl_in, const float* __restrict__ Wr_in,
                                               float* __restrict__ Wl_out, float* __restrict__ Wr_out,
                                               const float* __restrict__ Wsh, const float* __restrict__ Wwt,
                                               float* __restrict__ M0,
                                               int* __restrict__ cnt, int* __restrict__ fill,
                                               float* __restrict__ deg0, int* __restrict__ gtotal) {
    if (blockIdx.x < 2) {
        spectral_block((int)blockIdx.x, Wl_in, Wr_in, Wl_out, Wr_out, Wsh, Wwt, M0);
        return;
    }
    int i = (blockIdx.x - 2) * 256 + threadIdx.x;
    if (i == 0) *gtotal = 0;
    if (i < NN) { cnt[i] = 0; fill[i] = 0; deg0[i] = 0.0f; }
}

// ---------------- MFMA GEMM: multi-tile grid-stride + N column-split
template<int K, int N, int NH, bool ELU, bool HIST>
__global__ __launch_bounds__(256) void k_gemm(const float* __restrict__ X,
                                              const float* __restrict__ W,
                                              const float* __restrict__ bias,
                                              float* __restrict__ out,
                                              const int* __restrict__ row, int* __restrict__ cnt) {
    constexpr int KP = K + 8;
    constexpr int NT = NH / 16;
    constexpr int KS = K / 32;
    constexpr int NHALVES = N / NH;
    __shared__ __align__(16) unsigned short whi[NH * KP];
    __shared__ __align__(16) unsigned short wlo[NH * KP];
    int tid = threadIdx.x;
    if (HIST) {   // independent atomics first; latency hides behind GEMM
        for (int e = blockIdx.x * 256 + tid; e < E2; e += gridDim.x * 256)
            atomicAdd(&cnt[row[e]], 1);
    }
    const int ch = blockIdx.x % NHALVES;
    const int tstream = blockIdx.x / NHALVES;
    const int nstreams = gridDim.x / NHALVES;
    for (int i = tid; i < NH * K; i += 256) {
        float v = W[ch * NH * K + i];
        int r = i / K, c = i % K;
        unsigned h = rne_bf16(v);
        whi[r * KP + c] = (unsigned short)h;
        wlo[r * KP + c] = (unsigned short)rne_bf16(v - __uint_as_float(h << 16));
    }
    __syncthreads();
    int wave = tid >> 6, lane = tid & 63;
    int quad = lane >> 4, r16 = lane & 15;
    for (int t = tstream; t < NTILES; t += nstreams) {
        long m = (long)t * 64 + wave * 16 + r16;
        long mc = m < NN ? m : (NN - 1);
        const float* xrow = X + mc * K + quad * 8;
        short8 ah[KS], al[KS];
#pragma unroll
        for (int ks = 0; ks < KS; ++ks) {
            const float4* xp = (const float4*)(xrow + ks * 32);
            float4 p0 = xp[0], p1 = xp[1];
            float xv[8] = {p0.x, p0.y, p0.z, p0.w, p1.x, p1.y, p1.z, p1.w};
#pragma unroll
            for (int j = 0; j < 8; ++j) {
                unsigned h = rne_bf16(xv[j]);
                ah[ks][j] = (short)h;
                al[ks][j] = (short)rne_bf16(xv[j] - __uint_as_float(h << 16));
            }
        }
        long mbase = (long)t * 64 + wave * 16 + quad * 4;
#pragma unroll
        for (int tt = 0; tt < NT; ++tt) {
            f32x4 acc = (f32x4){0.f, 0.f, 0.f, 0.f};
#pragma unroll
            for (int ks = 0; ks < KS; ++ks) {
                int ro = (tt * 16 + r16) * KP + ks * 32 + quad * 8;
                short8 bh = *(const short8*)&whi[ro];
                short8 bl = *(const short8*)&wlo[ro];
                acc = __builtin_amdgcn_mfma_f32_16x16x32_bf16(ah[ks], bh, acc, 0, 0, 0);
                acc = __builtin_amdgcn_mfma_f32_16x16x32_bf16(al[ks], bh, acc, 0, 0, 0);
                acc = __builtin_amdgcn_mfma_f32_16x16x32_bf16(ah[ks], bl, acc, 0, 0, 0);
            }
            // C/D layout: col = lane&15, row = quad*4 + reg [m89-verified]
            int coln = ch * NH + tt * 16 + r16;
            float b = bias[coln];
#pragma unroll
            for (int rr = 0; rr < 4; ++rr) {
                long mm = mbase + rr;
                if (mm < NN) {
                    float v = acc[rr] + b;
                    if (ELU) v = eluf(v);
                    out[mm * N + coln] = v;
                }
            }
        }
    }
}

// ---------------- y8 GEMM (layer 0): y/proj = xc @ M0^T via MFMA; pack epilogue from acc regs.
// Lane r16 holds output cols {c, c+32, c+64} in acc[tt], acc[tt+2], acc[tt+4] (tt<2) -> direct
// yA/yB pack; acc[6] cols 96..99 -> proj (r16<4 writes component r16; AoS float4 layout kept).
// Blocks >= NTILES do the CSR fill (same as old filly8 fill branch).
__global__ __launch_bounds__(256) void k_ygemm(const float* __restrict__ X,
                                               const float* __restrict__ M,
                                               unsigned* __restrict__ yA, unsigned short* __restrict__ yB,
                                               float4* __restrict__ proj,
                                               const int* __restrict__ row, const int* __restrict__ start,
                                               int* __restrict__ fill, int* __restrict__ eslot) {
    constexpr int K = 96, KP = 104, NH = 112, NT = 7, KS = 3;
    int tid = threadIdx.x;
    if (blockIdx.x >= NTILES) {   // CSR fill branch
        int e = (blockIdx.x - NTILES) * 256 + tid;
        if (e < E2) {
            int u = row[e];
            eslot[e] = start[u] + atomicAdd(&fill[u], 1);
        }
        return;
    }
    __shared__ __align__(16) unsigned short whi[NH * KP];
    __shared__ __align__(16) unsigned short wlo[NH * KP];
    for (int i = tid; i < NH * K; i += 256) {
        float v = M[i];
        int r = i / K, c = i % K;
        unsigned h = rne_bf16(v);
        whi[r * KP + c] = (unsigned short)h;
        wlo[r * KP + c] = (unsigned short)rne_bf16(v - __uint_as_float(h << 16));
    }
    __syncthreads();
    int wave = tid >> 6, lane = tid & 63;
    int quad = lane >> 4, r16 = lane & 15;
    int t = blockIdx.x;
    long m = (long)t * 64 + wave * 16 + r16;
    long mc = m < NN ? m : (NN - 1);
    const float* xrow = X + mc * K + quad * 8;
    short8 ah[KS], al[KS];
#pragma unroll
    for (int ks = 0; ks < KS; ++ks) {
        const float4* xp = (const float4*)(xrow + ks * 32);
        float4 p0 = xp[0], p1 = xp[1];
        float xv[8] = {p0.x, p0.y, p0.z, p0.w, p1.x, p1.y, p1.z, p1.w};
#pragma unroll
        for (int j = 0; j < 8; ++j) {
            unsigned h = rne_bf16(xv[j]);
            ah[ks][j] = (short)h;
            al[ks][j] = (short)rne_bf16(xv[j] - __uint_as_float(h << 16));
        }
    }
    f32x4 acc[NT];
#pragma unroll
    for (int tt = 0; tt < NT; ++tt) acc[tt] = (f32x4){0.f, 0.f, 0.f, 0.f};
#pragma unroll
    for (int tt = 0; tt < NT; ++tt) {
#pragma unroll
        for (int ks = 0; ks < KS; ++ks) {
            int ro = (tt * 16 + r16) * KP + ks * 32 + quad * 8;
            short8 bh = *(const short8*)&whi[ro];
            short8 bl = *(const short8*)&wlo[ro];
            acc[tt] = __builtin_amdgcn_mfma_f32_16x16x32_bf16(ah[ks], bh, acc[tt], 0, 0, 0);
            acc[tt] = __builtin_amdgcn_mfma_f32_16x16x32_bf16(al[ks], bh, acc[tt], 0, 0, 0);
            acc[tt] = __builtin_amdgcn_mfma_f32_16x16x32_bf16(ah[ks], bl, acc[tt], 0, 0, 0);
        }
    }
    long mbase = (long)t * 64 + wave * 16 + quad * 4;
#pragma unroll
    for (int rr = 0; rr < 4; ++rr) {
        long mm = mbase + rr;
        if (mm < NN) {
#pragma unroll
            for (int tt = 0; tt < 2; ++tt) {
                int c = tt * 16 + r16;
                yA[mm * 32 + c] = rne_bf16(acc[tt][rr]) | (rne_bf16(acc[tt + 2][rr]) << 16);
                yB[mm * 32 + c] = (unsigned short)rne_bf16(acc[tt + 4][rr]);
            }
            if (r16 < 4) ((float*)proj)[mm * 4 + r16] = acc[6][rr];
        }
    }
}

// ---------------- single-pass scan: local prefix + atomic grid offset -> absolute start
__global__ __launch_bounds__(256) void k_scan(const int* __restrict__ cnt, int* __restrict__ start,
                                              int* __restrict__ gtotal) {
    __shared__ int s[256];
    __shared__ int soff;
    int b = blockIdx.x, t = threadIdx.x;
    int i = b * 256 + t;
    int v = (i < NN) ? cnt[i] : 0;
    s[t] = v;
    __syncthreads();
    for (int off = 1; off < 256; off <<= 1) {
        int add = (t >= off) ? s[t - off] : 0;
        __syncthreads();
        s[t] += add;
        __syncthreads();
    }
    if (t == 255) soff = atomicAdd(gtotal, s[255]);   // chunk order nondeterministic; slots stay disjoint
    __syncthreads();
    if (i < NN) start[i] = s[t] - v + soff;
}

// ---------------- per-edge coefficients, 8B packed meta + degree
__global__ __launch_bounds__(256) void k_coef(const int* __restrict__ row, const int* __restrict__ col,
                                              const int* __restrict__ eslot,
                                              const float4* __restrict__ proj,
                                              uint2* __restrict__ meta, float* __restrict__ deg) {
    int e = blockIdx.x * 256 + threadIdx.x;
    if (e >= E0) return;
    int u = row[e], v = col[e];
    float4 pu = proj[u], pv = proj[v];
    float a_e = ftanh(pu.x + pv.y);
    float a_r = ftanh(pv.x + pu.y);
    float wd_e = fsig(pu.z + pv.w);
    float wd_r = fsig(pv.z + pu.w);
    float w = wd_e * wd_r;
    float w2 = w * w;
    float ie = 1.0f / (1.0f + a_e * a_e), ir = 1.0f / (1.0f + a_r * a_r);
    float ce = (1.0f - a_e * a_e) * ie, se = 2.0f * a_e * ie;
    float cr = (1.0f - a_r * a_r) * ir, sr = 2.0f * a_r * ir;
    float C = ce * cr + se * sr;   // T_e = Q_e^T Q_rev ; T_rev = T_e^T -> (C,-S)
    float S = ce * sr - se * cr;
    unsigned cb = rne_bf16(C), sb = rne_bf16(S), wb = rne_bf16(w2);
    meta[eslot[e]]      = make_uint2(cb | (sb << 16), (unsigned)v | (wb << 16));
    meta[eslot[e + E0]] = make_uint2(cb | ((sb ^ 0x8000u) << 16), (unsigned)u | (wb << 16));
    atomicAdd(&deg[u], w2);
    atomicAdd(&deg[v], w2);
}

// ---------------- gather body (2 nodes/wave, 32-lane halves)
// Coefficients staged in LDS float4 (1 ds_write_b128 per edge), then the j-loop reads
// them via ONE same-address ds_read_b128 broadcast per edge (replaces 4 ds_bpermute).
// Same-half-warp write->read needs no barrier (intra-wave LDS ordering).
__device__ __forceinline__ void gather_accum(int s0, int ec, int c,
                                             const uint2* __restrict__ meta,
                                             const float* __restrict__ deg, float du,
                                             const unsigned* __restrict__ yA,
                                             const unsigned short* __restrict__ yB,
                                             float4* __restrict__ ecoef,   // this node's 32-slot LDS
                                             float& acc0, float& acc1, float& acc2) {
    for (int bs = 0; bs < ec; bs += 32) {
        int nb2 = min(32, ec - bs);
        if (c < nb2) {
            uint2 mt = meta[s0 + bs + c];
            int vj = (int)(mt.y & 0xffffu);
            float w2 = __uint_as_float(mt.y & 0xffff0000u);
            float Cv = __uint_as_float(mt.x << 16);
            float Sv = __uint_as_float(mt.x & 0xffff0000u);
            float dv = deg[vj];
            float dvi = dv > 0.0f ? rsqrtf(fmaxf(dv, 1e-30f)) : 0.0f;
            float cnl = w2 * du * dvi;
            ecoef[c] = make_float4(cnl * Cv, cnl * Sv, cnl, __int_as_float(vj));
        }
        int j4 = nb2 & ~3;
        int j = 0;
        for (; j < j4; j += 4) {
#pragma unroll
            for (int jj = 0; jj < 4; ++jj) {
                float4 e = ecoef[j + jj];          // same-addr broadcast, conflict-free
                int v = __float_as_int(e.w);
                unsigned ua = yA[v * 32 + c];
                unsigned ub = (unsigned)yB[v * 32 + c];
                float y0 = __uint_as_float(ua << 16);
                float y1 = __uint_as_float(ua & 0xffff0000u);
                float y2 = __uint_as_float(ub << 16);
                acc0 = fmaf(e.x, y0, acc0);
                acc0 = fmaf(-e.y, y1, acc0);
                acc1 = fmaf(e.y, y0, acc1);
                acc1 = fmaf(e.x, y1, acc1);
                acc2 = fmaf(e.z, y2, acc2);
            }
        }
        for (; j < nb2; ++j) {
            float4 e = ecoef[j];
            int v = __float_as_int(e.w);
            unsigned ua = yA[v * 32 + c];
            unsigned ub = (unsigned)yB[v * 32 + c];
            float y0 = __uint_as_float(ua << 16);
            float y1 = __uint_as_float(ua & 0xffff0000u);
            float y2 = __uint_as_float(ub << 16);
            acc0 = fmaf(e.x, y0, acc0);
            acc0 = fmaf(-e.y, y1, acc0);
            acc1 = fmaf(e.y, y0, acc1);
            acc1 = fmaf(e.x, y1, acc1);
            acc2 = fmaf(e.z, y2, acc2);
        }
    }
}

// ---------------- gather layer 0 + residual + FUSED y8 layer 1 (8 nodes/block, 2/wave)
__global__ __launch_bounds__(256) void k_gatherY(const int* __restrict__ start,
                                                 const int* __restrict__ cnt,
                                                 const uint2* __restrict__ meta,
                                                 const float* __restrict__ deg0,
                                                 const unsigned* __restrict__ yA0,
                                                 const unsigned short* __restrict__ yB0,
                                                 const float* __restrict__ eps,
                                                 float* __restrict__ xc,
                                                 const float* __restrict__ Wl, const float* __restrict__ Wr,
                                                 const float* __restrict__ Wsh, const float* __restrict__ Wwt,
                                                 unsigned* __restrict__ yA1, unsigned short* __restrict__ yB1,
                                                 float4* __restrict__ proj, float* __restrict__ deg1) {
    __shared__ float wrs[32 * 33];
    __shared__ float wls[9];
    __shared__ float xcs[8][96];
    __shared__ float ws1[192], wt[192];
    __shared__ float4 ecoef[8][32];
    int tid = threadIdx.x;
    int node = tid >> 5, c = tid & 31;
    int n = blockIdx.x * 8 + node;                 // NGROUPS*8 == NN: always in range
    // issue scalar per-node loads before staging so they overlap it
    int s0 = start[n], ec = cnt[n];
    float dn = deg0[n];
    for (int i = tid; i < 1024; i += 256) wrs[(i >> 5) * 33 + (i & 31)] = Wr[i];
    if (tid < 9) wls[tid] = Wl[tid];
    if (tid < 192) {
        ws1[tid] = Wsh[(1 * 3 + 1) * 192 + tid];   // layer 1 sheaf row
        wt[tid]  = Wwt[1 * 192 + tid];
    }
    __syncthreads();                               // weight staging visible to all waves
    float du = dn > 0.0f ? rsqrtf(fmaxf(dn, 1e-30f)) : 0.0f;
    float acc0 = 0, acc1 = 0, acc2 = 0;
    gather_accum(s0, ec, c, meta, deg0, du, yA0, yB0, ecoef[node], acc0, acc1, acc2);
    float diag = dn > 0.0f ? 1.0f : 0.0f;
    unsigned ua = yA0[n * 32 + c];
    unsigned ub = (unsigned)yB0[n * 32 + c];
    float oy0 = __uint_as_float(ua << 16);
    float oy1 = __uint_as_float(ua & 0xffff0000u);
    float oy2 = __uint_as_float(ub << 16);
    float c0 = 1.0f + tanhf(eps[0]);
    float c1 = 1.0f + tanhf(eps[1]);
    float c2 = 1.0f + tanhf(eps[2]);
    int base = n * 96 + c;
    float nx0 = c0 * xc[base]      - eluf(diag * oy0 - acc0);
    float nx1 = c1 * xc[base + 32] - eluf(diag * oy1 - acc1);
    float nx2 = c2 * xc[base + 64] - eluf(diag * oy2 - acc2);
    xc[base] = nx0; xc[base + 32] = nx1; xc[base + 64] = nx2;
    if (c == 0) deg1[n] = 0.0f;                    // zero next layer's degree
    xcs[node][c] = nx0; xcs[node][32 + c] = nx1; xcs[node][64 + c] = nx2;
    // NO __syncthreads: layer-1 epilogue reads only xcs[node], written by this same
    // half-warp (intra-wave LDS ordering); waves stay decoupled from slow gathers.
    // ---- layer-1 projections (own channels in registers) ----
    float a1 = nx0 * ws1[c] + nx1 * ws1[32 + c] + nx2 * ws1[64 + c];
    float a2 = nx0 * ws1[96 + c] + nx1 * ws1[128 + c] + nx2 * ws1[160 + c];
    float a3 = nx0 * wt[c] + nx1 * wt[32 + c] + nx2 * wt[64 + c];
    float a4 = nx0 * wt[96 + c] + nx1 * wt[128 + c] + nx2 * wt[160 + c];
#pragma unroll
    for (int off = 16; off; off >>= 1) {
        a1 += __shfl_xor(a1, off);
        a2 += __shfl_xor(a2, off);
        a3 += __shfl_xor(a3, off);
        a4 += __shfl_xor(a4, off);
    }
    if (c == 0) proj[n] = make_float4(a1, a2, a3, a4);
    // ---- layer-1 y ----
    {
        float t0 = 0, t1 = 0, t2 = 0;
        const float* wr = &wrs[c * 33];
        const float* xr = xcs[node];
#pragma unroll
        for (int h = 0; h < 32; ++h) {
            float w = wr[h];
            t0 = fmaf(xr[h], w, t0);
            t1 = fmaf(xr[32 + h], w, t1);
            t2 = fmaf(xr[64 + h], w, t2);
        }
        float o0 = wls[0] * t0 + wls[1] * t1 + wls[2] * t2;
        float o1 = wls[3] * t0 + wls[4] * t1 + wls[5] * t2;
        float o2 = wls[6] * t0 + wls[7] * t1 + wls[8] * t2;
        yA1[n * 32 + c] = rne_bf16(o0) | (rne_bf16(o1) << 16);
        yB1[n * 32 + c] = (unsigned short)rne_bf16(o2);
    }
}

// ---------------- plain gather + residual (layer 1)
__global__ __launch_bounds__(256) void k_gather(const int* __restrict__ start,
                                                const int* __restrict__ cnt,
                                                const uint2* __restrict__ meta,
                                                const float* __restrict__ deg,
                                                const unsigned* __restrict__ yA,
                                                const unsigned short* __restrict__ yB,
                                                const float* __restrict__ eps,
                                                int layer, float* __restrict__ xc) {
    __shared__ float4 ecoef[8][32];
    int tid = threadIdx.x;
    int node = tid >> 5, c = tid & 31;
    int n = blockIdx.x * 8 + node;
    if (n >= NN) return;
    int s0 = start[n], ec = cnt[n];
    float dn = deg[n];
    float du = dn > 0.0f ? rsqrtf(fmaxf(dn, 1e-30f)) : 0.0f;
    float acc0 = 0, acc1 = 0, acc2 = 0;
    gather_accum(s0, ec, c, meta, deg, du, yA, yB, ecoef[node], acc0, acc1, acc2);
    float diag = dn > 0.0f ? 1.0f : 0.0f;
    unsigned ua = yA[n * 32 + c];
    unsigned ub = (unsigned)yB[n * 32 + c];
    float oy0 = __uint_as_float(ua << 16);
    float oy1 = __uint_as_float(ua & 0xffff0000u);
    float oy2 = __uint_as_float(ub << 16);
    float c0 = 1.0f + tanhf(eps[layer * 3 + 0]);
    float c1 = 1.0f + tanhf(eps[layer * 3 + 1]);
    float c2 = 1.0f + tanhf(eps[layer * 3 + 2]);
    int base = n * 96 + c;
    float z0 = eluf(diag * oy0 - acc0);
    float z1 = eluf(diag * oy1 - acc1);
    float z2 = eluf(diag * oy2 - acc2);
    xc[base]      = c0 * xc[base]      - z0;
    xc[base + 32] = c1 * xc[base + 32] - z1;
    xc[base + 64] = c2 * xc[base + 64] - z2;
}

extern "C" void kernel_launch(void* const* d_in, const int* in_sizes, int n_in,
                              void* d_out, int out_size, void* d_ws, size_t ws_size,
                              hipStream_t stream) {
    const float* x     = (const float*)d_in[0];
    const int*   ei    = (const int*)d_in[1];
    const float* W1    = (const float*)d_in[2];
    const float* b1    = (const float*)d_in[3];
    const float* W2    = (const float*)d_in[4];
    const float* b2    = (const float*)d_in[5];
    const float* Wl    = (const float*)d_in[6];
    const float* Wr    = (const float*)d_in[7];
    const float* eps   = (const float*)d_in[8];
    const float* Wsh   = (const float*)d_in[9];
    const float* Wwt   = (const float*)d_in[10];
    float* out = (float*)d_out;
    const int* row = ei;        // edge_index[0]
    const int* col = ei + E2;   // edge_index[1]

    char* pc = (char*)d_ws;
    float* xc     = (float*)pc;          pc += (size_t)NN * 96 * 4;
    uint2* meta   = (uint2*)pc;          pc += (size_t)E2 * 8;
    unsigned* yA0 = (unsigned*)pc;       pc += (size_t)NN * 32 * 4;
    unsigned* yA1 = (unsigned*)pc;       pc += (size_t)NN * 32 * 4;
    unsigned short* yB0 = (unsigned short*)pc; pc += (size_t)NN * 32 * 2;
    unsigned short* yB1 = (unsigned short*)pc; pc += (size_t)NN * 32 * 2;
    pc = (char*)(((size_t)pc + 15) & ~(size_t)15);
    float4* proj  = (float4*)pc;         pc += (size_t)NN * 16;
    float* deg0   = (float*)pc;          pc += (size_t)NN * 4;
    float* deg1   = (float*)pc;          pc += (size_t)NN * 4;
    float* Wl_n   = (float*)pc;          pc += 32 * 4;
    float* Wr_n   = (float*)pc;          pc += 2048 * 4;
    float* M0     = (float*)pc;          pc += (size_t)112 * 96 * 4;
    int* cnt      = (int*)pc;            pc += (size_t)NN * 4;
    int* start    = (int*)pc;            pc += (size_t)NN * 4;
    int* fill     = (int*)pc;            pc += (size_t)NN * 4;
    int* eslot    = (int*)pc;            pc += (size_t)E2 * 4;
    int* gtotal   = (int*)pc;            pc += 4;

    // 9 dispatches total
    k_setup<<<NCHUNK + 2, 256, 0, stream>>>(Wl, Wr, Wl_n, Wr_n, Wsh, Wwt, M0,
                                            cnt, fill, deg0, gtotal);
    k_gemm<128, 96, 48, true, true><<<1024, 256, 0, stream>>>(x, W1, b1, xc, row, cnt);
    k_scan<<<NCHUNK, 256, 0, stream>>>(cnt, start, gtotal);
    k_ygemm<<<NTILES + EB, 256, 0, stream>>>(xc, M0, yA0, yB0, proj, row, start, fill, eslot);
    k_coef<<<(E0 + 255) / 256, 256, 0, stream>>>(row, col, eslot, proj, meta, deg0);
    k_gatherY<<<NGROUPS, 256, 0, stream>>>(start, cnt, meta, deg0, yA0, yB0, eps, xc,
                                           Wl_n + 9, Wr_n + 1024, Wsh, Wwt, yA1, yB1, proj, deg1);
    k_coef<<<(E0 + 255) / 256, 256, 0, stream>>>(row, col, eslot, proj, meta, deg1);
    k_gather<<<NGROUPS, 256, 0, stream>>>(start, cnt, meta, deg1, yA1, yB1, eps, 1, xc);
    k_gemm<96, 32, 32, false, false><<<782, 256, 0, stream>>>(xc, W2, b2, out, nullptr, nullptr);
}

// Round 8
// 304.106 us; speedup vs baseline: 1.1256x; 1.0176x over previous
//
#include <hip/hip_runtime.h>

#define NN 50000
#define E0 200000
#define E2 400000
#define NGROUPS ((NN + 7) / 8)      // 6250 (×8 = 50000 exactly)
#define NCHUNK  ((NN + 255) / 256)  // 196
#define NTILES  ((NN + 63) / 64)    // 782
#define EB      ((E2 + 255) / 256)  // 1563

typedef __attribute__((ext_vector_type(8))) short short8;
typedef __attribute__((ext_vector_type(4))) float f32x4;

__device__ __forceinline__ float eluf(float x) { return x > 0.0f ? x : expm1f(x); }
__device__ __forceinline__ float fsig(float x) { return 1.0f / (1.0f + __expf(-x)); }
__device__ __forceinline__ float ftanh(float x) {
    float e = __expf(-2.0f * x);
    return (1.0f - e) / (1.0f + e);
}
__device__ __forceinline__ unsigned rne_bf16(float x) {
    unsigned u = __float_as_uint(x);
    return (u + 0x7fffu + ((u >> 16) & 1u)) >> 16;
}

// ---------------- single-wave spectral norm + (l==0) build M0 = [kron(Wl,Wr); proj rows; 0-pad]
// lane r holds u[r]; matvecs via shfl broadcast; stride-33 LDS conflict-free both ways.
__device__ __forceinline__ void spectral_block(int l, const float* __restrict__ Wl_in,
                                               const float* __restrict__ Wr_in,
                                               float* __restrict__ Wl_out, float* __restrict__ Wr_out,
                                               const float* __restrict__ Wsh, const float* __restrict__ Wwt,
                                               float* __restrict__ M0) {
    __shared__ float W[32 * 33];
    __shared__ float sscal;
    __shared__ float wl_s[9];
    int t = threadIdx.x;
    for (int i = t; i < 1024; i += 256) W[(i >> 5) * 33 + (i & 31)] = Wr_in[l * 1024 + i];
    __syncthreads();
    if (t < 32) {
        float u = 0.17677669529663688f;     // 1/sqrt(32), lane r holds u[r]
        for (int it = 0; it < 20; ++it) {
            float v = 0.f;                   // v[c] = sum_r W[r][c] * u[r]  (lane c)
#pragma unroll 8
            for (int r = 0; r < 32; ++r) v = fmaf(W[r * 33 + t], __shfl(u, r, 32), v);
            float s = v * v;
#pragma unroll
            for (int off = 16; off; off >>= 1) s += __shfl_xor(s, off, 32);
            v *= 1.0f / (sqrtf(s) + 1e-12f);
            float u2 = 0.f;                  // u2[r] = sum_c W[r][c] * v[c]  (lane r)
#pragma unroll 8
            for (int c = 0; c < 32; ++c) u2 = fmaf(W[t * 33 + c], __shfl(v, c, 32), u2);
            s = u2 * u2;
#pragma unroll
            for (int off = 16; off; off >>= 1) s += __shfl_xor(s, off, 32);
            u = u2 * (1.0f / (sqrtf(s) + 1e-12f));
        }
        // sigma: v = W^T u (final); s = ||v||^2 ; 1/sigma = (sqrt(s)+1e-12)/s  (matches ref)
        float v = 0.f;
#pragma unroll 8
        for (int r = 0; r < 32; ++r) v = fmaf(W[r * 33 + t], __shfl(u, r, 32), v);
        float s = v * v;
#pragma unroll
        for (int off = 16; off; off >>= 1) s += __shfl_xor(s, off, 32);
        if (t == 0) sscal = (sqrtf(s) + 1e-12f) / s;
    } else if (t == 64) {                    // Wl 3x3 power iteration on wave 1, concurrent
        float M[9];
        for (int i = 0; i < 9; ++i) M[i] = Wl_in[l * 9 + i];
        float u[3] = {0.5773502691896258f, 0.5773502691896258f, 0.5773502691896258f};
        float v[3], u2[3];
        for (int it = 0; it < 20; ++it) {
            float s = 0;
            for (int c = 0; c < 3; ++c) { v[c] = M[c] * u[0] + M[3 + c] * u[1] + M[6 + c] * u[2]; s += v[c] * v[c]; }
            float inv = 1.0f / (sqrtf(s) + 1e-12f);
            for (int c = 0; c < 3; ++c) v[c] *= inv;
            s = 0;
            for (int r = 0; r < 3; ++r) { u2[r] = M[r * 3] * v[0] + M[r * 3 + 1] * v[1] + M[r * 3 + 2] * v[2]; s += u2[r] * u2[r]; }
            inv = 1.0f / (sqrtf(s) + 1e-12f);
            for (int r = 0; r < 3; ++r) u[r] = u2[r] * inv;
        }
        float s = 0;
        for (int c = 0; c < 3; ++c) { v[c] = M[c] * u[0] + M[3 + c] * u[1] + M[6 + c] * u[2]; s += v[c] * v[c]; }
        float inv = (sqrtf(s) + 1e-12f) / s;
        for (int i = 0; i < 9; ++i) { float w = M[i] * inv; Wl_out[l * 9 + i] = w; wl_s[i] = w; }
    }
    __syncthreads();
    float invs = sscal;
    for (int i = t; i < 1024; i += 256) Wr_out[l * 1024 + i] = W[(i >> 5) * 33 + (i & 31)] * invs;
    if (l == 0) {
        // rows 0..95: kron(Wl, Wr_scaled): M0[e*32+cc][f*32+h] = Wl[e,f]*Wr[cc,h]
        for (int i = t; i < 96 * 96; i += 256) {
            int yc = i / 96, k = i % 96;
            int e = yc >> 5, cc = yc & 31, f = k >> 5, h = k & 31;
            M0[yc * 96 + k] = wl_s[e * 3 + f] * W[cc * 33 + h] * invs;
        }
        // rows 96..99: [ws1 row0; ws1 row1; wt row0; wt row1] (layer 0)
        for (int i = t; i < 4 * 96; i += 256) {
            int r = i / 96, k = i % 96;
            float v = (r < 2) ? Wsh[192 + r * 96 + k] : Wwt[(r - 2) * 96 + k];
            M0[(96 + r) * 96 + k] = v;
        }
        // rows 100..111: zero pad
        for (int i = t; i < 12 * 96; i += 256) M0[100 * 96 + i] = 0.f;
    }
}

// ---------------- setup: blocks 0,1 = spectral norm per layer (+M0); rest zero counters
__global__ __launch_bounds__(256) void k_setup(const float* __restrict__ Wl_in, const float* __restrict__ Wr_in,
                                               float* __restrict__ Wl_out, float* __restrict__ Wr_out,
                                               const float* __restrict__ Wsh, const float* __restrict__ Wwt,
                                               float* __restrict__ M0,
                                               int* __restrict__ cnt, int* __restrict__ fill,
                                               float* __restrict__ deg0, int* __restrict__ gtotal) {
    if (blockIdx.x < 2) {
        spectral_block((int)blockIdx.x, Wl_in, Wr_in, Wl_out, Wr_out, Wsh, Wwt, M0);
        return;
    }
    int i = (blockIdx.x - 2) * 256 + threadIdx.x;
    if (i == 0) *gtotal = 0;
    if (i < NN) { cnt[i] = 0; fill[i] = 0; deg0[i] = 0.0f; }
}

// ---------------- MFMA GEMM: multi-tile grid-stride + N column-split
template<int K, int N, int NH, bool ELU, bool HIST>
__global__ __launch_bounds__(256) void k_gemm(const float* __restrict__ X,
                                              const float* __restrict__ W,
                                              const float* __restrict__ bias,
                                              float* __restrict__ out,
                                              const int* __restrict__ row, int* __restrict__ cnt) {
    constexpr int KP = K + 8;
    constexpr int NT = NH / 16;
    constexpr int KS = K / 32;
    constexpr int NHALVES = N / NH;
    __shared__ __align__(16) unsigned short whi[NH * KP];
    __shared__ __align__(16) unsigned short wlo[NH * KP];
    int tid = threadIdx.x;
    if (HIST) {   // independent atomics first; latency hides behind GEMM
        for (int e = blockIdx.x * 256 + tid; e < E2; e += gridDim.x * 256)
            atomicAdd(&cnt[row[e]], 1);
    }
    const int ch = blockIdx.x % NHALVES;
    const int tstream = blockIdx.x / NHALVES;
    const int nstreams = gridDim.x / NHALVES;
    for (int i = tid; i < NH * K; i += 256) {
        float v = W[ch * NH * K + i];
        int r = i / K, c = i % K;
        unsigned h = rne_bf16(v);
        whi[r * KP + c] = (unsigned short)h;
        wlo[r * KP + c] = (unsigned short)rne_bf16(v - __uint_as_float(h << 16));
    }
    __syncthreads();
    int wave = tid >> 6, lane = tid & 63;
    int quad = lane >> 4, r16 = lane & 15;
    for (int t = tstream; t < NTILES; t += nstreams) {
        long m = (long)t * 64 + wave * 16 + r16;
        long mc = m < NN ? m : (NN - 1);
        const float* xrow = X + mc * K + quad * 8;
        short8 ah[KS], al[KS];
#pragma unroll
        for (int ks = 0; ks < KS; ++ks) {
            const float4* xp = (const float4*)(xrow + ks * 32);
            float4 p0 = xp[0], p1 = xp[1];
            float xv[8] = {p0.x, p0.y, p0.z, p0.w, p1.x, p1.y, p1.z, p1.w};
#pragma unroll
            for (int j = 0; j < 8; ++j) {
                unsigned h = rne_bf16(xv[j]);
                ah[ks][j] = (short)h;
                al[ks][j] = (short)rne_bf16(xv[j] - __uint_as_float(h << 16));
            }
        }
        long mbase = (long)t * 64 + wave * 16 + quad * 4;
#pragma unroll
        for (int tt = 0; tt < NT; ++tt) {
            f32x4 acc = (f32x4){0.f, 0.f, 0.f, 0.f};
#pragma unroll
            for (int ks = 0; ks < KS; ++ks) {
                int ro = (tt * 16 + r16) * KP + ks * 32 + quad * 8;
                short8 bh = *(const short8*)&whi[ro];
                short8 bl = *(const short8*)&wlo[ro];
                acc = __builtin_amdgcn_mfma_f32_16x16x32_bf16(ah[ks], bh, acc, 0, 0, 0);
                acc = __builtin_amdgcn_mfma_f32_16x16x32_bf16(al[ks], bh, acc, 0, 0, 0);
                acc = __builtin_amdgcn_mfma_f32_16x16x32_bf16(ah[ks], bl, acc, 0, 0, 0);
            }
            // C/D layout: col = lane&15, row = quad*4 + reg [m89-verified]
            int coln = ch * NH + tt * 16 + r16;
            float b = bias[coln];
#pragma unroll
            for (int rr = 0; rr < 4; ++rr) {
                long mm = mbase + rr;
                if (mm < NN) {
                    float v = acc[rr] + b;
                    if (ELU) v = eluf(v);
                    out[mm * N + coln] = v;
                }
            }
        }
    }
}

// ---------------- y8 GEMM (layer 0): y/proj = xc @ M0^T via MFMA; pack epilogue from acc regs.
// Lane r16 holds output cols {c, c+32, c+64} in acc[tt], acc[tt+2], acc[tt+4] (tt<2) -> direct
// yA/yB pack; acc[6] cols 96..99 -> proj (r16<4 writes component r16; AoS float4 layout kept).
// Blocks >= NTILES do the CSR fill (same as old filly8 fill branch).
__global__ __launch_bounds__(256) void k_ygemm(const float* __restrict__ X,
                                               const float* __restrict__ M,
                                               unsigned* __restrict__ yA, unsigned short* __restrict__ yB,
                                               float4* __restrict__ proj,
                                               const int* __restrict__ row, const int* __restrict__ start,
                                               int* __restrict__ fill, int* __restrict__ eslot) {
    constexpr int K = 96, KP = 104, NH = 112, NT = 7, KS = 3;
    int tid = threadIdx.x;
    if (blockIdx.x >= NTILES) {   // CSR fill branch
        int e = (blockIdx.x - NTILES) * 256 + tid;
        if (e < E2) {
            int u = row[e];
            eslot[e] = start[u] + atomicAdd(&fill[u], 1);
        }
        return;
    }
    __shared__ __align__(16) unsigned short whi[NH * KP];
    __shared__ __align__(16) unsigned short wlo[NH * KP];
    for (int i = tid; i < NH * K; i += 256) {
        float v = M[i];
        int r = i / K, c = i % K;
        unsigned h = rne_bf16(v);
        whi[r * KP + c] = (unsigned short)h;
        wlo[r * KP + c] = (unsigned short)rne_bf16(v - __uint_as_float(h << 16));
    }
    __syncthreads();
    int wave = tid >> 6, lane = tid & 63;
    int quad = lane >> 4, r16 = lane & 15;
    int t = blockIdx.x;
    long m = (long)t * 64 + wave * 16 + r16;
    long mc = m < NN ? m : (NN - 1);
    const float* xrow = X + mc * K + quad * 8;
    short8 ah[KS], al[KS];
#pragma unroll
    for (int ks = 0; ks < KS; ++ks) {
        const float4* xp = (const float4*)(xrow + ks * 32);
        float4 p0 = xp[0], p1 = xp[1];
        float xv[8] = {p0.x, p0.y, p0.z, p0.w, p1.x, p1.y, p1.z, p1.w};
#pragma unroll
        for (int j = 0; j < 8; ++j) {
            unsigned h = rne_bf16(xv[j]);
            ah[ks][j] = (short)h;
            al[ks][j] = (short)rne_bf16(xv[j] - __uint_as_float(h << 16));
        }
    }
    f32x4 acc[NT];
#pragma unroll
    for (int tt = 0; tt < NT; ++tt) acc[tt] = (f32x4){0.f, 0.f, 0.f, 0.f};
#pragma unroll
    for (int tt = 0; tt < NT; ++tt) {
#pragma unroll
        for (int ks = 0; ks < KS; ++ks) {
            int ro = (tt * 16 + r16) * KP + ks * 32 + quad * 8;
            short8 bh = *(const short8*)&whi[ro];
            short8 bl = *(const short8*)&wlo[ro];
            acc[tt] = __builtin_amdgcn_mfma_f32_16x16x32_bf16(ah[ks], bh, acc[tt], 0, 0, 0);
            acc[tt] = __builtin_amdgcn_mfma_f32_16x16x32_bf16(al[ks], bh, acc[tt], 0, 0, 0);
            acc[tt] = __builtin_amdgcn_mfma_f32_16x16x32_bf16(ah[ks], bl, acc[tt], 0, 0, 0);
        }
    }
    long mbase = (long)t * 64 + wave * 16 + quad * 4;
#pragma unroll
    for (int rr = 0; rr < 4; ++rr) {
        long mm = mbase + rr;
        if (mm < NN) {
#pragma unroll
            for (int tt = 0; tt < 2; ++tt) {
                int c = tt * 16 + r16;
                yA[mm * 32 + c] = rne_bf16(acc[tt][rr]) | (rne_bf16(acc[tt + 2][rr]) << 16);
                yB[mm * 32 + c] = (unsigned short)rne_bf16(acc[tt + 4][rr]);
            }
            if (r16 < 4) ((float*)proj)[mm * 4 + r16] = acc[6][rr];
        }
    }
}

// ---------------- single-pass scan: local prefix + atomic grid offset -> absolute start
__global__ __launch_bounds__(256) void k_scan(const int* __restrict__ cnt, int* __restrict__ start,
                                              int* __restrict__ gtotal) {
    __shared__ int s[256];
    __shared__ int soff;
    int b = blockIdx.x, t = threadIdx.x;
    int i = b * 256 + t;
    int v = (i < NN) ? cnt[i] : 0;
    s[t] = v;
    __syncthreads();
    for (int off = 1; off < 256; off <<= 1) {
        int add = (t >= off) ? s[t - off] : 0;
        __syncthreads();
        s[t] += add;
        __syncthreads();
    }
    if (t == 255) soff = atomicAdd(gtotal, s[255]);   // chunk order nondeterministic; slots stay disjoint
    __syncthreads();
    if (i < NN) start[i] = s[t] - v + soff;
}

// ---------------- per-edge coefficients, 8B packed meta + degree
__global__ __launch_bounds__(256) void k_coef(const int* __restrict__ row, const int* __restrict__ col,
                                              const int* __restrict__ eslot,
                                              const float4* __restrict__ proj,
                                              uint2* __restrict__ meta, float* __restrict__ deg) {
    int e = blockIdx.x * 256 + threadIdx.x;
    if (e >= E0) return;
    int u = row[e], v = col[e];
    float4 pu = proj[u], pv = proj[v];
    float a_e = ftanh(pu.x + pv.y);
    float a_r = ftanh(pv.x + pu.y);
    float wd_e = fsig(pu.z + pv.w);
    float wd_r = fsig(pv.z + pu.w);
    float w = wd_e * wd_r;
    float w2 = w * w;
    float ie = 1.0f / (1.0f + a_e * a_e), ir = 1.0f / (1.0f + a_r * a_r);
    float ce = (1.0f - a_e * a_e) * ie, se = 2.0f * a_e * ie;
    float cr = (1.0f - a_r * a_r) * ir, sr = 2.0f * a_r * ir;
    float C = ce * cr + se * sr;   // T_e = Q_e^T Q_rev ; T_rev = T_e^T -> (C,-S)
    float S = ce * sr - se * cr;
    unsigned cb = rne_bf16(C), sb = rne_bf16(S), wb = rne_bf16(w2);
    meta[eslot[e]]      = make_uint2(cb | (sb << 16), (unsigned)v | (wb << 16));
    meta[eslot[e + E0]] = make_uint2(cb | ((sb ^ 0x8000u) << 16), (unsigned)u | (wb << 16));
    atomicAdd(&deg[u], w2);
    atomicAdd(&deg[v], w2);
}

// ---------------- gather body (2 nodes/wave, 32-lane halves), 8-deep load pipeline
// Coefficients staged in LDS float4 (1 ds_write_b128 per edge); ALL 32 lanes write
// (zero coef + v=0 pads lanes >= nb2) so the j-loop runs fixed 8-wide chunks:
// 8 independent ds_read_b128 + 16 independent global loads in flight before the FMA
// block. Padded slots contribute exactly 0 (fmaf(0,finite)=0); real-edge accumulation
// order unchanged (bit-identical). Same-half-warp write->read needs no barrier.
__device__ __forceinline__ void gather_accum(int s0, int ec, int c,
                                             const uint2* __restrict__ meta,
                                             const float* __restrict__ deg, float du,
                                             const unsigned* __restrict__ yA,
                                             const unsigned short* __restrict__ yB,
                                             float4* __restrict__ ecoef,   // this node's 32-slot LDS
                                             float& acc0, float& acc1, float& acc2) {
    const unsigned* yac = yA + c;
    const unsigned short* ybc = yB + c;
    for (int bs = 0; bs < ec; bs += 32) {
        int nb2 = min(32, ec - bs);
        float4 my = make_float4(0.f, 0.f, 0.f, 0.f);   // pad: coef 0, v bits = 0 -> loads y[0]
        if (c < nb2) {
            uint2 mt = meta[s0 + bs + c];
            int vj = (int)(mt.y & 0xffffu);
            float w2 = __uint_as_float(mt.y & 0xffff0000u);
            float Cv = __uint_as_float(mt.x << 16);
            float Sv = __uint_as_float(mt.x & 0xffff0000u);
            float dv = deg[vj];
            float dvi = dv > 0.0f ? rsqrtf(fmaxf(dv, 1e-30f)) : 0.0f;
            float cnl = w2 * du * dvi;
            my = make_float4(cnl * Cv, cnl * Sv, cnl, __int_as_float(vj));
        }
        ecoef[c] = my;
        int jceil = (nb2 + 7) & ~7;
        for (int j = 0; j < jceil; j += 8) {
#pragma unroll
            for (int jj = 0; jj < 8; ++jj) {
                float4 e = ecoef[j + jj];          // same-addr broadcast, conflict-free
                int v = __float_as_int(e.w);
                unsigned ua = yac[v * 32];
                unsigned ub = (unsigned)ybc[v * 32];
                float y0 = __uint_as_float(ua << 16);
                float y1 = __uint_as_float(ua & 0xffff0000u);
                float y2 = __uint_as_float(ub << 16);
                acc0 = fmaf(e.x, y0, acc0);
                acc0 = fmaf(-e.y, y1, acc0);
                acc1 = fmaf(e.y, y0, acc1);
                acc1 = fmaf(e.x, y1, acc1);
                acc2 = fmaf(e.z, y2, acc2);
            }
        }
    }
}

// ---------------- gather layer 0 + residual + FUSED y8 layer 1 (8 nodes/block, 2/wave)
__global__ __launch_bounds__(256) void k_gatherY(const int* __restrict__ start,
                                                 const int* __restrict__ cnt,
                                                 const uint2* __restrict__ meta,
                                                 const float* __restrict__ deg0,
                                                 const unsigned* __restrict__ yA0,
                                                 const unsigned short* __restrict__ yB0,
                                                 const float* __restrict__ eps,
                                                 float* __restrict__ xc,
                                                 const float* __restrict__ Wl, const float* __restrict__ Wr,
                                                 const float* __restrict__ Wsh, const float* __restrict__ Wwt,
                                                 unsigned* __restrict__ yA1, unsigned short* __restrict__ yB1,
                                                 float4* __restrict__ proj, float* __restrict__ deg1) {
    __shared__ float wrs[32 * 33];
    __shared__ float wls[9];
    __shared__ float xcs[8][96];
    __shared__ float ws1[192], wt[192];
    __shared__ float4 ecoef[8][32];
    int tid = threadIdx.x;
    int node = tid >> 5, c = tid & 31;
    int n = blockIdx.x * 8 + node;                 // NGROUPS*8 == NN: always in range
    // issue scalar per-node loads before staging so they overlap it
    int s0 = start[n], ec = cnt[n];
    float dn = deg0[n];
    for (int i = tid; i < 1024; i += 256) wrs[(i >> 5) * 33 + (i & 31)] = Wr[i];
    if (tid < 9) wls[tid] = Wl[tid];
    if (tid < 192) {
        ws1[tid] = Wsh[(1 * 3 + 1) * 192 + tid];   // layer 1 sheaf row
        wt[tid]  = Wwt[1 * 192 + tid];
    }
    __syncthreads();                               // weight staging visible to all waves
    float du = dn > 0.0f ? rsqrtf(fmaxf(dn, 1e-30f)) : 0.0f;
    float acc0 = 0, acc1 = 0, acc2 = 0;
    gather_accum(s0, ec, c, meta, deg0, du, yA0, yB0, ecoef[node], acc0, acc1, acc2);
    float diag = dn > 0.0f ? 1.0f : 0.0f;
    unsigned ua = yA0[n * 32 + c];
    unsigned ub = (unsigned)yB0[n * 32 + c];
    float oy0 = __uint_as_float(ua << 16);
    float oy1 = __uint_as_float(ua & 0xffff0000u);
    float oy2 = __uint_as_float(ub << 16);
    float c0 = 1.0f + tanhf(eps[0]);
    float c1 = 1.0f + tanhf(eps[1]);
    float c2 = 1.0f + tanhf(eps[2]);
    int base = n * 96 + c;
    float nx0 = c0 * xc[base]      - eluf(diag * oy0 - acc0);
    float nx1 = c1 * xc[base + 32] - eluf(diag * oy1 - acc1);
    float nx2 = c2 * xc[base + 64] - eluf(diag * oy2 - acc2);
    xc[base] = nx0; xc[base + 32] = nx1; xc[base + 64] = nx2;
    if (c == 0) deg1[n] = 0.0f;                    // zero next layer's degree
    xcs[node][c] = nx0; xcs[node][32 + c] = nx1; xcs[node][64 + c] = nx2;
    // NO __syncthreads: layer-1 epilogue reads only xcs[node], written by this same
    // half-warp (intra-wave LDS ordering); waves stay decoupled from slow gathers.
    // ---- layer-1 projections (own channels in registers) ----
    float a1 = nx0 * ws1[c] + nx1 * ws1[32 + c] + nx2 * ws1[64 + c];
    float a2 = nx0 * ws1[96 + c] + nx1 * ws1[128 + c] + nx2 * ws1[160 + c];
    float a3 = nx0 * wt[c] + nx1 * wt[32 + c] + nx2 * wt[64 + c];
    float a4 = nx0 * wt[96 + c] + nx1 * wt[128 + c] + nx2 * wt[160 + c];
#pragma unroll
    for (int off = 16; off; off >>= 1) {
        a1 += __shfl_xor(a1, off);
        a2 += __shfl_xor(a2, off);
        a3 += __shfl_xor(a3, off);
        a4 += __shfl_xor(a4, off);
    }
    if (c == 0) proj[n] = make_float4(a1, a2, a3, a4);
    // ---- layer-1 y ----
    {
        float t0 = 0, t1 = 0, t2 = 0;
        const float* wr = &wrs[c * 33];
        const float* xr = xcs[node];
#pragma unroll
        for (int h = 0; h < 32; ++h) {
            float w = wr[h];
            t0 = fmaf(xr[h], w, t0);
            t1 = fmaf(xr[32 + h], w, t1);
            t2 = fmaf(xr[64 + h], w, t2);
        }
        float o0 = wls[0] * t0 + wls[1] * t1 + wls[2] * t2;
        float o1 = wls[3] * t0 + wls[4] * t1 + wls[5] * t2;
        float o2 = wls[6] * t0 + wls[7] * t1 + wls[8] * t2;
        yA1[n * 32 + c] = rne_bf16(o0) | (rne_bf16(o1) << 16);
        yB1[n * 32 + c] = (unsigned short)rne_bf16(o2);
    }
}

// ---------------- plain gather + residual (layer 1)
__global__ __launch_bounds__(256) void k_gather(const int* __restrict__ start,
                                                const int* __restrict__ cnt,
                                                const uint2* __restrict__ meta,
                                                const float* __restrict__ deg,
                                                const unsigned* __restrict__ yA,
                                                const unsigned short* __restrict__ yB,
                                                const float* __restrict__ eps,
                                                int layer, float* __restrict__ xc) {
    __shared__ float4 ecoef[8][32];
    int tid = threadIdx.x;
    int node = tid >> 5, c = tid & 31;
    int n = blockIdx.x * 8 + node;
    if (n >= NN) return;
    int s0 = start[n], ec = cnt[n];
    float dn = deg[n];
    float du = dn > 0.0f ? rsqrtf(fmaxf(dn, 1e-30f)) : 0.0f;
    float acc0 = 0, acc1 = 0, acc2 = 0;
    gather_accum(s0, ec, c, meta, deg, du, yA, yB, ecoef[node], acc0, acc1, acc2);
    float diag = dn > 0.0f ? 1.0f : 0.0f;
    unsigned ua = yA[n * 32 + c];
    unsigned ub = (unsigned)yB[n * 32 + c];
    float oy0 = __uint_as_float(ua << 16);
    float oy1 = __uint_as_float(ua & 0xffff0000u);
    float oy2 = __uint_as_float(ub << 16);
    float c0 = 1.0f + tanhf(eps[layer * 3 + 0]);
    float c1 = 1.0f + tanhf(eps[layer * 3 + 1]);
    float c2 = 1.0f + tanhf(eps[layer * 3 + 2]);
    int base = n * 96 + c;
    float z0 = eluf(diag * oy0 - acc0);
    float z1 = eluf(diag * oy1 - acc1);
    float z2 = eluf(diag * oy2 - acc2);
    xc[base]      = c0 * xc[base]      - z0;
    xc[base + 32] = c1 * xc[base + 32] - z1;
    xc[base + 64] = c2 * xc[base + 64] - z2;
}

extern "C" void kernel_launch(void* const* d_in, const int* in_sizes, int n_in,
                              void* d_out, int out_size, void* d_ws, size_t ws_size,
                              hipStream_t stream) {
    const float* x     = (const float*)d_in[0];
    const int*   ei    = (const int*)d_in[1];
    const float* W1    = (const float*)d_in[2];
    const float* b1    = (const float*)d_in[3];
    const float* W2    = (const float*)d_in[4];
    const float* b2    = (const float*)d_in[5];
    const float* Wl    = (const float*)d_in[6];
    const float* Wr    = (const float*)d_in[7];
    const float* eps   = (const float*)d_in[8];
    const float* Wsh   = (const float*)d_in[9];
    const float* Wwt   = (const float*)d_in[10];
    float* out = (float*)d_out;
    const int* row = ei;        // edge_index[0]
    const int* col = ei + E2;   // edge_index[1]

    char* pc = (char*)d_ws;
    float* xc     = (float*)pc;          pc += (size_t)NN * 96 * 4;
    uint2* meta   = (uint2*)pc;          pc += (size_t)E2 * 8;
    unsigned* yA0 = (unsigned*)pc;       pc += (size_t)NN * 32 * 4;
    unsigned* yA1 = (unsigned*)pc;       pc += (size_t)NN * 32 * 4;
    unsigned short* yB0 = (unsigned short*)pc; pc += (size_t)NN * 32 * 2;
    unsigned short* yB1 = (unsigned short*)pc; pc += (size_t)NN * 32 * 2;
    pc = (char*)(((size_t)pc + 15) & ~(size_t)15);
    float4* proj  = (float4*)pc;         pc += (size_t)NN * 16;
    float* deg0   = (float*)pc;          pc += (size_t)NN * 4;
    float* deg1   = (float*)pc;          pc += (size_t)NN * 4;
    float* Wl_n   = (float*)pc;          pc += 32 * 4;
    float* Wr_n   = (float*)pc;          pc += 2048 * 4;
    float* M0     = (float*)pc;          pc += (size_t)112 * 96 * 4;
    int* cnt      = (int*)pc;            pc += (size_t)NN * 4;
    int* start    = (int*)pc;            pc += (size_t)NN * 4;
    int* fill     = (int*)pc;            pc += (size_t)NN * 4;
    int* eslot    = (int*)pc;            pc += (size_t)E2 * 4;
    int* gtotal   = (int*)pc;            pc += 4;

    // 9 dispatches total
    k_setup<<<NCHUNK + 2, 256, 0, stream>>>(Wl, Wr, Wl_n, Wr_n, Wsh, Wwt, M0,
                                            cnt, fill, deg0, gtotal);
    k_gemm<128, 96, 48, true, true><<<1024, 256, 0, stream>>>(x, W1, b1, xc, row, cnt);
    k_scan<<<NCHUNK, 256, 0, stream>>>(cnt, start, gtotal);
    k_ygemm<<<NTILES + EB, 256, 0, stream>>>(xc, M0, yA0, yB0, proj, row, start, fill, eslot);
    k_coef<<<(E0 + 255) / 256, 256, 0, stream>>>(row, col, eslot, proj, meta, deg0);
    k_gatherY<<<NGROUPS, 256, 0, stream>>>(start, cnt, meta, deg0, yA0, yB0, eps, xc,
                                           Wl_n + 9, Wr_n + 1024, Wsh, Wwt, yA1, yB1, proj, deg1);
    k_coef<<<(E0 + 255) / 256, 256, 0, stream>>>(row, col, eslot, proj, meta, deg1);
    k_gather<<<NGROUPS, 256, 0, stream>>>(start, cnt, meta, deg1, yA1, yB1, eps, 1, xc);
    k_gemm<96, 32, 32, false, false><<<782, 256, 0, stream>>>(xc, W2, b2, out, nullptr, nullptr);
}